// Round 14
// baseline (8857.133 us; speedup 1.0000x reference)
//
#include <hip/hip_runtime.h>
#include <stdint.h>

// ---------------------------------------------------------------------------
// LEM-style noisy RNN. T=128 x DIV=10 sequential steps, B=256, H=256.
// Round 14: poll-loop surgery. Hot poll loop touches ONLY the same-XCD L2
// payload copy (sc0, ~0.15us RT); L3 copy checked every 8th iter (fallback,
// correctness never depends on XCD mapping). Producer stores L2 copy first.
// Consumer scatters payload PAIRS as 4 aligned u32 LDS writes (was 8 u16).
// Structure: 16 groups x 4 WGs (Y0,Y1,Z0,Z1), E2 LDS-resident, Wz in regs,
// in-register phase fusion, E2=Wic+Wh fold, HN=Wh@ny + XI=Wi@x precompute.
// ---------------------------------------------------------------------------

typedef __attribute__((ext_vector_type(8))) short bf16x8_t;
typedef __attribute__((ext_vector_type(4))) float f32x4_t;
typedef __attribute__((ext_vector_type(4))) unsigned int u32x4_t;
typedef unsigned short u16;

#define R_LDS_BYTES 147712

__device__ __forceinline__ float bf2f(u16 b) {
  union { uint32_t u; float f; } v; v.u = ((uint32_t)b) << 16; return v.f;
}
__device__ __forceinline__ u16 f2bf(float f) {
  union { float f; uint32_t u; } v; v.f = f;
  uint32_t x = v.u;
  return (u16)((x + 0x7FFFu + ((x >> 16) & 1u)) >> 16);   // RNE
}
__device__ __forceinline__ f32x4_t mfma16(bf16x8_t a, bf16x8_t b, f32x4_t c) {
  return __builtin_amdgcn_mfma_f32_16x16x32_bf16(a, b, c, 0, 0, 0);
}
__device__ __forceinline__ float sigm(float x) { return 1.0f / (1.0f + __expf(-x)); }
__device__ __forceinline__ float tanh_f(float x) {
  float t = __expf(-2.0f * fabsf(x));
  float r = (1.0f - t) / (1.0f + t);
  return x < 0.0f ? -r : r;
}

// A-frag slot for (k in [0,256), row m in [0,16))
__device__ __forceinline__ int fslot(int k, int m) {
  return ((k >> 5) * 512) + (((((k & 15) >> 2) << 4) | m) << 3) +
         ((k & 3) | (((k >> 4) & 1) << 2));
}
// MFMA 16x16x32 bf16 A-frag K-position for lane l, elem e
__device__ __forceinline__ int fragK(int l, int e) {
  return ((l >> 4) << 2) + (e & 3) + ((e >> 2) << 4);
}

// ---- dual-path transport (L2 fast path first, L3 authoritative) ----
__device__ __forceinline__ void publish(uint32_t* p3, uint32_t* p2,
                                        uint32_t w0, uint32_t w1, uint32_t seq) {
  u32x4_t pay; pay.x = w0; pay.y = seq; pay.z = w1; pay.w = seq;
  asm volatile("global_store_dwordx4 %1, %2, off sc0\n\t"
               "global_store_dwordx4 %0, %2, off sc0 sc1"
               :: "v"(p3), "v"(p2), "v"(pay) : "memory");
}
__device__ __forceinline__ bool try2_l2(const uint32_t* p, uint32_t seq,
                                        u32x4_t* a, u32x4_t* b) {
  u32x4_t x, y;
  asm volatile("global_load_dwordx4 %0, %2, off sc0\n\t"
               "global_load_dwordx4 %1, %3, off sc0\n\t"
               "s_waitcnt vmcnt(0)"
               : "=&v"(x), "=&v"(y) : "v"(p), "v"(p + 4) : "memory");
  if (x.y == seq && x.w == seq && y.y == seq && y.w == seq) { *a = x; *b = y; return true; }
  return false;
}
__device__ __forceinline__ bool try2_l3(const uint32_t* p, uint32_t seq,
                                        u32x4_t* a, u32x4_t* b) {
  u32x4_t x, y;
  asm volatile("global_load_dwordx4 %0, %2, off sc0 sc1\n\t"
               "global_load_dwordx4 %1, %3, off sc0 sc1\n\t"
               "s_waitcnt vmcnt(0)"
               : "=&v"(x), "=&v"(y) : "v"(p), "v"(p + 4) : "memory");
  if (x.y == seq && x.w == seq && y.y == seq && y.w == seq) { *a = x; *b = y; return true; }
  return false;
}
__device__ __forceinline__ void pollpair_fast(const uint32_t* p2, const uint32_t* p3,
                                              uint32_t seq, u32x4_t* a, u32x4_t* b) {
  int it = 0;
  while (true) {
    if (try2_l2(p2, seq, a, b)) return;
    if ((++it & 7) == 0) {
      if (try2_l3(p3, seq, a, b)) return;
      __builtin_amdgcn_s_sleep(1);
    }
  }
}
// scatter a PAIR of C/D-order payload slots (j even: j, j+1) as 4 u32 writes.
// fslot(col+1,m) == fslot(col,m)+1 for even col -> adjacent u16s.
__device__ __forceinline__ void scatterPair(u16* dst, int j, u32x4_t pa, u32x4_t pb) {
  int wvp = (j >> 6) & 7, lp = j & 63, hf = j >> 9;
  int colp = hf * 128 + wvp * 16 + (lp & 15);   // even
  int mb = 4 * (lp >> 4);
  int base = fslot(colp, mb);                   // even
  uint32_t* d = (uint32_t*)(dst + base);
  d[0]  = (pa.x & 0xffffu) | ((pb.x & 0xffffu) << 16);
  d[4]  = (pa.x >> 16)     | (pb.x & 0xffff0000u);
  d[8]  = (pa.z & 0xffffu) | ((pb.z & 0xffffu) << 16);
  d[12] = (pa.z >> 16)     | (pb.z & 0xffff0000u);
}

// ---- JAX threefry2x32 (20 rounds) ----
__device__ __forceinline__ void threefry(uint32_t k0, uint32_t k1, uint32_t x0, uint32_t x1,
                                         uint32_t* o0, uint32_t* o1) {
  uint32_t ks2 = k0 ^ k1 ^ 0x1BD11BDAu;
  x0 += k0; x1 += k1;
#define TFR(rot) { x0 += x1; x1 = (x1 << rot) | (x1 >> (32 - rot)); x1 ^= x0; }
  TFR(13) TFR(15) TFR(26) TFR(6)   x0 += k1;  x1 += ks2 + 1u;
  TFR(17) TFR(29) TFR(16) TFR(24)  x0 += ks2; x1 += k0 + 2u;
  TFR(13) TFR(15) TFR(26) TFR(6)   x0 += k0;  x1 += k1 + 3u;
  TFR(17) TFR(29) TFR(16) TFR(24)  x0 += k1;  x1 += ks2 + 4u;
  TFR(13) TFR(15) TFR(26) TFR(6)   x0 += ks2; x1 += k0 + 5u;
#undef TFR
  *o0 = x0; *o1 = x1;
}

// bits -> N(0,1), matches jax.random.normal f32 (XLA erfinv poly)
__device__ __forceinline__ float bits2normal(uint32_t bits) {
  union { uint32_t u; float f; } cv; cv.u = 0x3F800000u | (bits >> 9);
  float f = cv.f - 1.0f;
  float u = fmaf(f, 2.0f, -0.99999994f);
  u = fmaxf(u, -0.99999994f);
  float w = -log1pf(-u * u);
  float p;
  if (w < 5.0f) {
    w = w - 2.5f;
    p = 2.81022636e-08f;
    p = fmaf(p, w, 3.43273939e-07f);
    p = fmaf(p, w, -3.5233877e-06f);
    p = fmaf(p, w, -4.39150654e-06f);
    p = fmaf(p, w, 0.00021858087f);
    p = fmaf(p, w, -0.00125372503f);
    p = fmaf(p, w, -0.00417768164f);
    p = fmaf(p, w, 0.246640727f);
    p = fmaf(p, w, 1.50140941f);
  } else {
    w = sqrtf(w) - 3.0f;
    p = -0.000200214257f;
    p = fmaf(p, w, 0.000100950558f);
    p = fmaf(p, w, 0.00134934322f);
    p = fmaf(p, w, -0.00367342844f);
    p = fmaf(p, w, 0.00573950773f);
    p = fmaf(p, w, -0.0076224613f);
    p = fmaf(p, w, 0.00943887047f);
    p = fmaf(p, w, 1.00167406f);
    p = fmaf(p, w, 2.83297682f);
  }
  return 1.41421354f * p * u;
}

// ---------------------------------------------------------------------------
__global__ void k_prep(const float* __restrict__ W_i, const float* __restrict__ W_c,
                       const float* __restrict__ b_i, const float* __restrict__ b_c,
                       float* __restrict__ Wic, float* __restrict__ bip) {
  __shared__ float wi[256];
  __shared__ float red[256];
  int o = blockIdx.x; int tid = threadIdx.x;
  wi[tid] = W_i[o * 256 + tid];
  __syncthreads();
  float acc = 0.f;
  for (int j = 0; j < 256; ++j) acc = fmaf(wi[j], W_c[j * 256 + tid], acc);
  Wic[(size_t)o * 256 + tid] = acc;
  red[tid] = wi[tid] * b_c[tid];
  __syncthreads();
  for (int s = 128; s > 0; s >>= 1) { if (tid < s) red[tid] += red[tid + s]; __syncthreads(); }
  if (tid == 0) bip[o] = b_i[o] + red[0];
}

__global__ void k_bias(const float* __restrict__ b_i, const float* __restrict__ bip,
                       const float* __restrict__ b_h,
                       float* __restrict__ biasD0, float* __restrict__ biasDn) {
  int c = blockIdx.x * 256 + threadIdx.x;
  float bh = (c < 512) ? b_h[c] : (c >= 768 ? b_h[c - 256] : 0.f);
  biasD0[c] = b_i[c] + bh;
  biasDn[c] = bip[c] + bh;
}

__global__ void k_packw(const float* __restrict__ srcA, int rowsA, const float* __restrict__ srcB,
                        u16* __restrict__ dst, int O, int K) {
  int t = blockIdx.x * blockDim.x + threadIdx.x;
  int KK = K >> 5;
  int total = (O >> 4) * KK * 64;
  if (t >= total) return;
  int l = t & 63; int kk = (t >> 6) % KK; int to = t / (64 * KK);
  int n = (to << 4) | (l & 15);
  int kb = (kk << 5) + ((l >> 4) << 2);
  const float* src = (n < rowsA) ? (srcA + (size_t)n * K) : (srcB + (size_t)(n - rowsA) * K);
  u16 out[8];
#pragma unroll
  for (int e = 0; e < 8; ++e) out[e] = f2bf(src[kb + (e & 3) + ((e >> 2) << 4)]);
  *reinterpret_cast<uint4*>(dst + (size_t)t * 8) = *reinterpret_cast<const uint4*>(out);
}

// E2 = Wic + Wh aligned (cols 0..511 -> Wh[c], 768..1023 -> Wh[c-256]), 64 tiles
__global__ void k_packe2(const float* __restrict__ Wic, const float* __restrict__ Wh,
                         u16* __restrict__ dst) {
  int t = blockIdx.x * blockDim.x + threadIdx.x;   // 64*8*64 = 32768
  int l = t & 63; int kk = (t >> 6) & 7; int to = t >> 9;
  int n = (to << 4) | (l & 15);
  int kb = (kk << 5) + ((l >> 4) << 2);
  u16 out[8];
#pragma unroll
  for (int e = 0; e < 8; ++e) {
    int k = kb + (e & 3) + ((e >> 2) << 4);
    float v = Wic[(size_t)n * 256 + k];
    if (n < 512) v += Wh[(size_t)n * 256 + k];
    else if (n >= 768) v += Wh[(size_t)(n - 256) * 256 + k];
    out[e] = f2bf(v);
  }
  *reinterpret_cast<uint4*>(dst + (size_t)t * 8) = *reinterpret_cast<const uint4*>(out);
}

__global__ void k_packa(const float* __restrict__ inp, int t0, int Tcc, u16* __restrict__ dst) {
  int t = blockIdx.x * blockDim.x + threadIdx.x;
  int total = Tcc * 16 * 8 * 64;
  if (t >= total) return;
  int l = t & 63; int kk = (t >> 6) & 7; int mt = (t >> 9) & 15; int tl = t >> 13;
  int b = (mt << 4) | (l & 15);
  int kb = (kk << 5) + ((l >> 4) << 2);
  const float* src = inp + ((size_t)(t0 + tl) * 256 + b) * 256;
  u16 out[8];
#pragma unroll
  for (int e = 0; e < 8; ++e) out[e] = f2bf(src[kb + (e & 3) + ((e >> 2) << 4)]);
  *reinterpret_cast<uint4*>(dst + (size_t)t * 8) = *reinterpret_cast<const uint4*>(out);
}

// noise gen; slot sl = global noise step gstep0+sl (gstep0 = t0*10-1)
__global__ void k_gen(u16* __restrict__ Apack, int gstep0) {
  int sl = blockIdx.x >> 7;
  int tb = (blockIdx.x & 127) * 1024 + threadIdx.x;   // [0, 131072)
  __shared__ uint32_t kf[2];
  if (threadIdx.x == 0) {
    uint32_t o0, o1;
    threefry(0u, 1234u, 0u, (uint32_t)(gstep0 + sl), &o0, &o1);
    kf[0] = o0; kf[1] = o1;
  }
  __syncthreads();
  int e = tb & 7; int l = (tb >> 3) & 63; int kk = (tb >> 9) & 15; int mt = tb >> 13;
  int b = (mt << 4) | (l & 15);
  int c = (kk << 5) + fragK(l, e);
  uint32_t i = (uint32_t)(b * 512 + c);
  uint32_t o0, o1;
  threefry(kf[0], kf[1], 0u, i, &o0, &o1);
  Apack[(size_t)sl * 131072 + tb] = f2bf(bits2normal(o0 ^ o1));
}

// S = tanh(noise @ Ws^T + b_s) -> Sny/Snz (per (g,half), C/D-row-mapped thread
// order), and nyA (n<256 in A-frag layout, input for k_hn).
__global__ __launch_bounds__(512) void k_sgemm(const u16* __restrict__ Apack,
                                               const u16* __restrict__ Wspack,
                                               const float* __restrict__ b_s,
                                               u16* __restrict__ Sny, u16* __restrict__ Snz,
                                               u16* __restrict__ nyA) {
  int sl = blockIdx.x; int nq = blockIdx.y;
  int l = threadIdx.x & 63; int wv = threadIdx.x >> 6;
  const u16* Ab = Apack + (size_t)sl * 131072;
#pragma unroll 1
  for (int mtl = 0; mtl < 2; ++mtl) {
    int mt = 2 * wv + mtl;
    bf16x8_t af[16];
#pragma unroll
    for (int kk = 0; kk < 16; ++kk)
      af[kk] = *reinterpret_cast<const bf16x8_t*>(Ab + ((size_t)(mt * 16 + kk) * 64 + l) * 8);
#pragma unroll 1
    for (int ntl = 0; ntl < 8; ++ntl) {
      int nt = nq * 8 + ntl;
      f32x4_t acc = {0.f, 0.f, 0.f, 0.f};
#pragma unroll
      for (int kk = 0; kk < 16; ++kk) {
        bf16x8_t bfr = *reinterpret_cast<const bf16x8_t*>(Wspack + ((size_t)(nt * 16 + kk) * 64 + l) * 8);
        acc = mfma16(af[kk], bfr, acc);
      }
      int n = (nt << 4) | (l & 15);
      float bs = b_s[n];
#pragma unroll
      for (int r = 0; r < 4; ++r) {
        int m = (mt << 4) + ((l >> 4) << 2) + r;
        u16 v = f2bf(tanh_f(acc[r] + bs));
        int g = m >> 4, row = m & 15;
        if (n >= 256) {
          int h = n - 256; int hz = h >> 7;
          int tidc = ((h >> 4) & 7) * 64 + ((row >> 2) << 4) + (h & 15);
          Snz[((((size_t)sl * 16 + g) * 2 + hz) * 512 + tidc) * 4 + (row & 3)] = v;
        } else {
          int hy = n >> 7;
          int tidc = ((n >> 4) & 7) * 64 + ((row >> 2) << 4) + (n & 15);
          Sny[((((size_t)sl * 16 + g) * 2 + hy) * 512 + tidc) * 4 + (row & 3)] = v;
          int kk2 = n >> 5;
          int la = (((n & 15) >> 2) << 4) | row;
          int ea = (n & 3) | (((n >> 4) & 1) << 2);
          nyA[(((size_t)sl * 16 + g) * 8 + kk2) * 512 + la * 8 + ea] = v;
        }
      }
    }
  }
}

// HN[j] = Wh @ ny(slot j), C/D-frag layout (bf16), 48 col-tiles.
__global__ __launch_bounds__(512) void k_hn(const u16* __restrict__ nyA,
                                            const u16* __restrict__ Epack,
                                            u16* __restrict__ HNpack, int t0) {
  int j = blockIdx.x; int nq = blockIdx.y;
  int l = threadIdx.x & 63; int wv = threadIdx.x >> 6;
  int nt = nq * 8 + wv;                      // [0,48)
  if (j == 0 && t0 == 0) {
    uint2 z = {0u, 0u};
#pragma unroll 1
    for (int mt = 0; mt < 16; ++mt)
      *reinterpret_cast<uint2*>(&HNpack[(((size_t)j * 16 + mt) * 48 + nt) * 256 + l * 4]) = z;
    return;
  }
  bf16x8_t bf[8];
  const u16* bp = Epack + (size_t)(64 + nt) * 4096 + (size_t)l * 8;
#pragma unroll
  for (int kk = 0; kk < 8; ++kk)
    bf[kk] = *reinterpret_cast<const bf16x8_t*>(bp + kk * 512);
#pragma unroll 1
  for (int mt = 0; mt < 16; ++mt) {
    const u16* ap = nyA + (((size_t)j * 16 + mt) * 8) * 512 + (size_t)l * 8;
    f32x4_t acc = {0.f, 0.f, 0.f, 0.f};
#pragma unroll
    for (int kk = 0; kk < 8; ++kk)
      acc = mfma16(*reinterpret_cast<const bf16x8_t*>(ap + kk * 512), bf[kk], acc);
    union { u16 h[4]; uint2 v; } o;
#pragma unroll
    for (int r = 0; r < 4; ++r) o.h[r] = f2bf(acc[r]);
    *reinterpret_cast<uint2*>(&HNpack[(((size_t)j * 16 + mt) * 48 + nt) * 256 + l * 4]) = o.v;
  }
}

// XI[tl][g] = x @ Wi^T, C/D-frag layout (bf16), 64 col-tiles.
__global__ __launch_bounds__(512) void k_xi(const u16* __restrict__ inpPack,
                                            const u16* __restrict__ Wipack,
                                            u16* __restrict__ XIpack) {
  int tl = blockIdx.x; int nb = blockIdx.y;
  int l = threadIdx.x & 63; int wv = threadIdx.x >> 6;
  int nt = nb * 8 + wv;                      // [0,64)
  bf16x8_t bf[8];
  const u16* bp = Wipack + (size_t)nt * 4096 + (size_t)l * 8;
#pragma unroll
  for (int kk = 0; kk < 8; ++kk)
    bf[kk] = *reinterpret_cast<const bf16x8_t*>(bp + kk * 512);
#pragma unroll 1
  for (int g = 0; g < 16; ++g) {
    const u16* ap = inpPack + (size_t)(tl * 16 + g) * 4096 + (size_t)l * 8;
    f32x4_t acc = {0.f, 0.f, 0.f, 0.f};
#pragma unroll
    for (int kk = 0; kk < 8; ++kk)
      acc = mfma16(*reinterpret_cast<const bf16x8_t*>(ap + kk * 512), bf[kk], acc);
    union { u16 h[4]; uint2 v; } o;
#pragma unroll
    for (int r = 0; r < 4; ++r) o.h[r] = f2bf(acc[r]);
    *reinterpret_cast<uint2*>(&XIpack[(((size_t)tl * 16 + g) * 64 + nt) * 256 + l * 4]) = o.v;
  }
}

// ---------------------------------------------------------------------------
// Recurrence, 64 WGs x 512. wgid = role*16 + g. role 0/1 = Y(hy), 2/3 = Z(hz).
__global__ __launch_bounds__(512, 2) void k_recur(
    const float* __restrict__ dt,
    const u16* __restrict__ Epack, const u16* __restrict__ Wzpack,
    const u16* __restrict__ E2pack, const u16* __restrict__ HNpack,
    const u16* __restrict__ XIpack,
    const float* __restrict__ biasD0, const float* __restrict__ biasDn,
    const float* __restrict__ b_z, const float* __restrict__ W_dt, const float* __restrict__ b_dt,
    const u16* __restrict__ Sny, const u16* __restrict__ Snz,
    u16* __restrict__ Ypack, float* __restrict__ ystate, float* __restrict__ ypstate,
    float* __restrict__ zstate,
    uint32_t* __restrict__ yexch, uint32_t* __restrict__ yexch2,
    uint32_t* __restrict__ zexch, uint32_t* __restrict__ zexch2,
    int t0, int Tcc)
{
  extern __shared__ char lds_raw[];
  u16* wlds = (u16*)lds_raw;            // 65536 u16 (128KB): E2 tiles
  u16* buf  = wlds + 65536;             // 8192 u16: Z: y-frag dbuf; Y: [0]=y frags, [4096]=z frags
  float* sc  = (float*)(buf + 8192);    // 48
  float* scP = sc + 48;                 // 16

  const int wgid = blockIdx.x;
  const int g = wgid & 15;
  const int role = wgid >> 4;
  const bool isY = role < 2;
  const int half = role & 1;
  const int tid = threadIdx.x;
  const int l = tid & 63;
  const int wv = tid >> 6;
  const int nsteps = Tcc * 10;
  const int m2b = 4 * (l >> 4);
  const int col = half * 128 + wv * 16 + (l & 15);
  const uint32_t gb = (uint32_t)(t0 * 10);

  int wiT0, whT0, hnT0, wiT1, whT1 = -1, hnT1 = -1;
  if (isY) {
    wiT0 = half * 8 + wv;       whT0 = 64 + wiT0;  hnT0 = wiT0;
    wiT1 = 32 + half * 8 + wv;
  } else {
    wiT0 = 16 + half * 8 + wv;  whT0 = 64 + wiT0;  hnT0 = wiT0;
    wiT1 = 48 + half * 8 + wv;  whT1 = 96 + half * 8 + wv;  hnT1 = 32 + half * 8 + wv;
  }
  float b0d0 = biasD0[wiT0 * 16 + (l & 15)], b0dn = biasDn[wiT0 * 16 + (l & 15)];
  float b1d0 = biasD0[wiT1 * 16 + (l & 15)], b1dn = biasDn[wiT1 * 16 + (l & 15)];

  // ---- preload E2 weight tiles into LDS ----
  for (int i = tid; i < 8192; i += 512) {
    int t = i >> 9; int o = (i & 511) << 3;
    int gt;
    if (isY) gt = (t < 8) ? (half * 8 + t) : (32 + half * 8 + (t - 8));
    else     gt = (t < 8) ? (16 + half * 8 + t) : (48 + half * 8 + (t - 8));
    *reinterpret_cast<uint4*>(wlds + t * 4096 + o) =
        *reinterpret_cast<const uint4*>(E2pack + (size_t)gt * 4096 + o);
  }

  float zc[4], yc[4], ylast[4];
  bf16x8_t wzf[8];
  float bzr = 0.f;
  float wdt0 = W_dt[0], wdt1 = W_dt[1], bdt0 = b_dt[0], bdt1 = b_dt[1];

  if (isY) {
    bzr = b_z[col];
#pragma unroll
    for (int kk = 0; kk < 8; ++kk)
      wzf[kk] = *reinterpret_cast<const bf16x8_t*>(
          Wzpack + (size_t)(half * 8 + wv) * 4096 + (size_t)kk * 512 + (size_t)l * 8);
    u16 v[4];
#pragma unroll
    for (int r = 0; r < 4; ++r) {
      int m2 = m2b + r;
      yc[r] = (t0 == 0) ? 0.f : ystate[(size_t)(g * 16 + m2) * 256 + col];
      ylast[r] = 0.f;
      float vv = (t0 == 0) ? 0.f : ypstate[(size_t)(g * 16 + m2) * 256 + col];
      v[r] = f2bf(vv);
    }
    int base = fslot(col, m2b);
    buf[base] = v[0]; buf[base + 8] = v[1]; buf[base + 16] = v[2]; buf[base + 24] = v[3];
    uint32_t w0 = (uint32_t)v[0] | ((uint32_t)v[1] << 16);
    uint32_t w1 = (uint32_t)v[2] | ((uint32_t)v[3] << 16);
    size_t so = ((size_t)g * 1024 + half * 512 + tid) * 4;     // buffer 0
    publish(yexch + so, yexch2 + so, w0, w1, gb + 1u);
  } else {
#pragma unroll
    for (int r = 0; r < 4; ++r)
      zc[r] = (t0 == 0) ? 0.f : zstate[(size_t)(g * 16 + m2b + r) * 256 + col];
  }

  if (!isY) {
    // =============== Z loop: 1 barrier/step ===============
    for (int s = 0; s < nsteps; ++s) {
      int d = s % 10;
      uint2 nsv = *reinterpret_cast<const uint2*>(
          Snz + ((((size_t)(s + 1) * 16 + g) * 2 + half) * 512 + tid) * 4);
      size_t HNs = ((size_t)s * 16 + g) * 48;
      uint2 hv0 = *reinterpret_cast<const uint2*>(HNpack + (HNs + hnT0) * 256 + l * 4);
      uint2 hv1 = *reinterpret_cast<const uint2*>(HNpack + (HNs + hnT1) * 256 + l * 4);
      uint2 xi0 = {0u, 0u}, xi1 = {0u, 0u};
      if (d == 0) {
        int tl = s / 10;
        size_t XIs = ((size_t)tl * 16 + g) * 64;
        xi0 = *reinterpret_cast<const uint2*>(XIpack + (XIs + wiT0) * 256 + l * 4);
        xi1 = *reinterpret_cast<const uint2*>(XIpack + (XIs + wiT1) * 256 + l * 4);
        if (tid < 16) {
          float dl = dt[(size_t)(t0 + tl) * 256 + g * 16 + tid] * 0.1f;
          sc[tid] = dl;
          sc[16 + tid] = sigm(fmaf(dl, wdt0, bdt0));
          sc[32 + tid] = sigm(fmaf(dl, wdt1, bdt1));
          int tp = t0 + tl - 1; if (tp < 0) tp = 0;
          scP[tid] = dt[(size_t)tp * 256 + g * 16 + tid] * 0.1f;
        }
      }
      uint32_t seq = gb + (uint32_t)s + 1u;
      // poll full y; paired scatter into parity buffer
      size_t bo = (((size_t)(s & 1) * 16 + g) * 1024 + 2 * tid) * 4;
      u32x4_t pa, pb;
      pollpair_fast(yexch2 + bo, yexch + bo, seq, &pa, &pb);
      u16* yb = buf + (s & 1) * 4096;
      scatterPair(yb, 2 * tid, pa, pb);
      __syncthreads();
      // ---- A ----
      bf16x8_t ay[8];
#pragma unroll
      for (int kk = 0; kk < 8; ++kk)
        ay[kk] = *reinterpret_cast<const bf16x8_t*>(yb + kk * 512 + l * 8);
      float scv[4];
#pragma unroll
      for (int r = 0; r < 4; ++r) scv[r] = (d == 0 ? scP[m2b + r] : sc[m2b + r]);
      f32x4_t a0 = {0.f, 0.f, 0.f, 0.f}, a1 = {0.f, 0.f, 0.f, 0.f};
      if (d == 0) {
        const u16* hp0 = Epack + (size_t)whT0 * 4096 + (size_t)l * 8;
        const u16* hp1 = Epack + (size_t)whT1 * 4096 + (size_t)l * 8;
#pragma unroll
        for (int kk = 0; kk < 8; ++kk)
          a0 = mfma16(ay[kk], *reinterpret_cast<const bf16x8_t*>(hp0 + kk * 512), a0);
#pragma unroll
        for (int kk = 0; kk < 8; ++kk)
          a1 = mfma16(ay[kk], *reinterpret_cast<const bf16x8_t*>(hp1 + kk * 512), a1);
      } else {
        const u16* w0p = wlds + wv * 4096 + l * 8;
        const u16* w1p = wlds + (8 + wv) * 4096 + l * 8;
#pragma unroll
        for (int kk = 0; kk < 8; ++kk)
          a0 = mfma16(ay[kk], *reinterpret_cast<const bf16x8_t*>(w0p + kk * 512), a0);
#pragma unroll
        for (int kk = 0; kk < 8; ++kk)
          a1 = mfma16(ay[kk], *reinterpret_cast<const bf16x8_t*>(w1p + kk * 512), a1);
      }
      const u16* h0 = (const u16*)&hv0; const u16* h1 = (const u16*)&hv1;
      const u16* x0 = (const u16*)&xi0; const u16* x1 = (const u16*)&xi1;
      // ---- B: z update, publish direct ----
      const u16* nzp = (const u16*)&nsv;
      u16 zv[4];
#pragma unroll
      for (int r = 0; r < 4; ++r) {
        int m2 = m2b + r;
        float r0 = a0[r] + (d == 0 ? (b0d0 + bf2f(x0[r])) : b0dn) + scv[r] * bf2f(h0[r]);
        float r1 = a1[r] + (d == 0 ? (b1d0 + bf2f(x1[r])) : b1dn) + scv[r] * bf2f(h1[r]);
        float ms = sc[32 + m2] * sigm(r0);
        float zn = (1.0f - ms) * zc[r] + ms * tanh_f(r1);
        zv[r] = f2bf(zn);
        zc[r] = fmaf(bf2f(nzp[r]), sc[m2], zn);
      }
      uint32_t w0z = (uint32_t)zv[0] | ((uint32_t)zv[1] << 16);
      uint32_t w1z = (uint32_t)zv[2] | ((uint32_t)zv[3] << 16);
      size_t so = (((size_t)(s & 1) * 16 + g) * 1024 + half * 512 + tid) * 4;
      publish(zexch + so, zexch2 + so, w0z, w1z, seq);
    }
#pragma unroll
    for (int r = 0; r < 4; ++r)
      zstate[(size_t)(g * 16 + m2b + r) * 256 + col] = zc[r];
  } else {
    // =============== Y loop: 2 barriers/step ===============
    for (int s = 0; s < nsteps; ++s) {
      int d = s % 10, tl = s / 10;
      uint2 nsv = *reinterpret_cast<const uint2*>(
          Sny + ((((size_t)(s + 1) * 16 + g) * 2 + half) * 512 + tid) * 4);
      size_t HNs = ((size_t)s * 16 + g) * 48;
      uint2 hv0 = *reinterpret_cast<const uint2*>(HNpack + (HNs + hnT0) * 256 + l * 4);
      uint2 xi0 = {0u, 0u}, xi1 = {0u, 0u};
      if (d == 0) {
        size_t XIs = ((size_t)tl * 16 + g) * 64;
        xi0 = *reinterpret_cast<const uint2*>(XIpack + (XIs + wiT0) * 256 + l * 4);
        xi1 = *reinterpret_cast<const uint2*>(XIpack + (XIs + wiT1) * 256 + l * 4);
        if (tid < 16) {
          float dl = dt[(size_t)(t0 + tl) * 256 + g * 16 + tid] * 0.1f;
          sc[tid] = dl;
          sc[16 + tid] = sigm(fmaf(dl, wdt0, bdt0));
          sc[32 + tid] = sigm(fmaf(dl, wdt1, bdt1));
          int tp = t0 + tl - 1; if (tp < 0) tp = 0;
          scP[tid] = dt[(size_t)tp * 256 + g * 16 + tid] * 0.1f;
        }
      }
      uint32_t seq = gb + (uint32_t)s + 1u;
      // poll other y half (self half written during previous C): 256 threads x pair
      if (tid < 256) {
        int j = (1 ^ half) * 512 + 2 * tid;
        size_t bo = (((size_t)(s & 1) * 16 + g) * 1024 + j) * 4;
        u32x4_t pa, pb;
        pollpair_fast(yexch2 + bo, yexch + bo, seq, &pa, &pb);
        scatterPair(buf, j, pa, pb);
      }
      __syncthreads();                                  // BAR_1
      // ---- A ----
      f32x4_t r0v, r1v;
      {
        bf16x8_t ay[8];
#pragma unroll
        for (int kk = 0; kk < 8; ++kk)
          ay[kk] = *reinterpret_cast<const bf16x8_t*>(buf + kk * 512 + l * 8);
        float scv[4];
#pragma unroll
        for (int r = 0; r < 4; ++r) scv[r] = (d == 0 ? scP[m2b + r] : sc[m2b + r]);
        f32x4_t a0 = {0.f, 0.f, 0.f, 0.f}, a1 = {0.f, 0.f, 0.f, 0.f};
        if (d == 0) {
          const u16* hp0 = Epack + (size_t)whT0 * 4096 + (size_t)l * 8;
#pragma unroll
          for (int kk = 0; kk < 8; ++kk)
            a0 = mfma16(ay[kk], *reinterpret_cast<const bf16x8_t*>(hp0 + kk * 512), a0);
        } else {
          const u16* w0p = wlds + wv * 4096 + l * 8;
          const u16* w1p = wlds + (8 + wv) * 4096 + l * 8;
#pragma unroll
          for (int kk = 0; kk < 8; ++kk)
            a0 = mfma16(ay[kk], *reinterpret_cast<const bf16x8_t*>(w0p + kk * 512), a0);
#pragma unroll
          for (int kk = 0; kk < 8; ++kk)
            a1 = mfma16(ay[kk], *reinterpret_cast<const bf16x8_t*>(w1p + kk * 512), a1);
        }
        const u16* h0 = (const u16*)&hv0;
        const u16* x0 = (const u16*)&xi0; const u16* x1 = (const u16*)&xi1;
#pragma unroll
        for (int r = 0; r < 4; ++r) {
          r0v[r] = a0[r] + (d == 0 ? (b0d0 + bf2f(x0[r])) : b0dn) + scv[r] * bf2f(h0[r]);
          r1v[r] = (d == 0) ? (b1d0 + bf2f(x1[r])) : (a1[r] + b1dn);
        }
      }
      // poll z (full), paired scatter
      {
        size_t bo = (((size_t)(s & 1) * 16 + g) * 1024 + 2 * tid) * 4;
        u32x4_t qa, qb;
        pollpair_fast(zexch2 + bo, zexch + bo, seq, &qa, &qb);
        scatterPair(buf + 4096, 2 * tid, qa, qb);
      }
      __syncthreads();                                  // BAR_2
      // ---- C ----
      bf16x8_t zfr[8];
#pragma unroll
      for (int kk = 0; kk < 8; ++kk)
        zfr[kk] = *reinterpret_cast<const bf16x8_t*>(buf + 4096 + kk * 512 + l * 8);
      f32x4_t acc = {0.f, 0.f, 0.f, 0.f};
#pragma unroll
      for (int kk = 0; kk < 8; ++kk) acc = mfma16(zfr[kk], wzf[kk], acc);
      const u16* nyp = (const u16*)&nsv;
      u16 yv[4], pv[4];
      int base = fslot(col, m2b);
#pragma unroll
      for (int r = 0; r < 4; ++r) {
        int m2 = m2b + r;
        float u = acc[r] + bzr + r1v[r];
        float msb = sc[16 + m2] * sigm(r0v[r]);
        float yn = (1.0f - msb) * yc[r] + msb * tanh_f(u);
        float ypn = fmaf(bf2f(nyp[r]), sc[m2], yn);
        yc[r] = ypn; ylast[r] = yn;
        yv[r] = f2bf(yn); pv[r] = f2bf(ypn);
        buf[base + 8 * r] = yv[r];                      // self-half y(s+1)
      }
      uint32_t wy0 = (uint32_t)yv[0] | ((uint32_t)yv[1] << 16);
      uint32_t wy1 = (uint32_t)yv[2] | ((uint32_t)yv[3] << 16);
      size_t so = (((size_t)((s + 1) & 1) * 16 + g) * 1024 + half * 512 + tid) * 4;
      publish(yexch + so, yexch2 + so, wy0, wy1, gb + (uint32_t)s + 2u);
      if (d == 9) {
        uint2 pp = {(uint32_t)pv[0] | ((uint32_t)pv[1] << 16),
                    (uint32_t)pv[2] | ((uint32_t)pv[3] << 16)};
        *reinterpret_cast<uint2*>(Ypack + (size_t)(tl * 16 + g) * 4096 + (half * 512 + tid) * 4) = pp;
      }
    }
#pragma unroll
    for (int r = 0; r < 4; ++r) {
      int m2 = m2b + r;
      ystate[(size_t)(g * 16 + m2) * 256 + col] = yc[r];
      ypstate[(size_t)(g * 16 + m2) * 256 + col] = ylast[r];
    }
  }
}

// out[t] = Y[t] @ W_c^T + b_c.  Ypack is C/D-order; transpose via LDS here.
__global__ __launch_bounds__(512) void k_out(const u16* __restrict__ Ypack, const u16* __restrict__ Wcpack,
                                             const float* __restrict__ b_c, float* __restrict__ out, int t0) {
  __shared__ u16 yl[4 * 4096];
  int tl = blockIdx.x; int mh = blockIdx.y;
  int tid = threadIdx.x; int l = tid & 63; int wv = tid >> 6;
  for (int i = tid; i < 4096; i += 512) {
    int pg = i >> 10; int j = i & 1023;
    uint2 v = *reinterpret_cast<const uint2*>(
        Ypack + ((size_t)(tl * 16 + mh * 4 + pg)) * 4096 + (size_t)j * 4);
    int wvp = (j >> 6) & 7, lp = j & 63, hf = j >> 9;
    int colp = hf * 128 + wvp * 16 + (lp & 15);
    int mb = 4 * (lp >> 4);
    int base = pg * 4096 + fslot(colp, mb);
    yl[base] = (u16)(v.x & 0xffffu);
    yl[base + 8] = (u16)(v.x >> 16);
    yl[base + 16] = (u16)(v.y & 0xffffu);
    yl[base + 24] = (u16)(v.y >> 16);
  }
  __syncthreads();
  int gl = wv >> 1; int nh = wv & 1;
  int mt = mh * 4 + gl;
  bf16x8_t af[8];
#pragma unroll
  for (int kk = 0; kk < 8; ++kk)
    af[kk] = *reinterpret_cast<const bf16x8_t*>(yl + gl * 4096 + kk * 512 + l * 8);
#pragma unroll 1
  for (int ntl = 0; ntl < 8; ++ntl) {
    int nt = nh * 8 + ntl;
    f32x4_t acc = {0.f, 0.f, 0.f, 0.f};
    const u16* bp = Wcpack + ((size_t)nt * 8 * 64 + l) * 8;
#pragma unroll
    for (int kk = 0; kk < 8; ++kk) {
      bf16x8_t bfr = *reinterpret_cast<const bf16x8_t*>(bp + kk * 512);
      acc = mfma16(af[kk], bfr, acc);
    }
    int n = (nt << 4) | (l & 15);
    float bc = b_c[n];
#pragma unroll
    for (int r = 0; r < 4; ++r) {
      int m = (mt << 4) + ((l >> 4) << 2) + r;
      out[((size_t)(t0 + tl) * 256 + m) * 256 + n] = acc[r] + bc;
    }
  }
}

// ---------------------------------------------------------------------------
extern "C" void kernel_launch(void* const* d_in, const int* in_sizes, int n_in,
                              void* d_out, int out_size, void* d_ws, size_t ws_size,
                              hipStream_t stream) {
  const float* input = (const float*)d_in[0];
  const float* dt    = (const float*)d_in[1];
  const float* W_i   = (const float*)d_in[2];
  const float* b_i   = (const float*)d_in[3];
  const float* W_h   = (const float*)d_in[4];
  const float* b_h   = (const float*)d_in[5];
  const float* W_z   = (const float*)d_in[6];
  const float* b_z   = (const float*)d_in[7];
  const float* W_dt  = (const float*)d_in[8];
  const float* b_dt  = (const float*)d_in[9];
  const float* W_c   = (const float*)d_in[10];
  const float* b_c   = (const float*)d_in[11];
  const float* W_s   = (const float*)d_in[12];
  const float* b_s   = (const float*)d_in[13];
  float* out = (float*)d_out;

  char* ws = (char*)d_ws;
  size_t off = 0;
  auto alloc = [&](size_t bytes) -> char* {
    char* p = ws + off; off = (off + bytes + 255) & ~(size_t)255; return p;
  };
  u16* Epack   = (u16*)alloc((size_t)112 * 4096 * 2);
  u16* Wipack  = (u16*)alloc((size_t)64 * 4096 * 2);
  u16* Wzpack  = (u16*)alloc((size_t)16 * 4096 * 2);
  u16* Wcpack  = (u16*)alloc((size_t)16 * 4096 * 2);
  u16* Wspack  = (u16*)alloc((size_t)32 * 16 * 512 * 2);
  u16* E2pack  = (u16*)alloc((size_t)64 * 4096 * 2);
  float* bip   = (float*)alloc(1024 * 4);
  float* biasD0= (float*)alloc(1024 * 4);
  float* biasDn= (float*)alloc(1024 * 4);
  float* Wic   = (float*)alloc((size_t)1024 * 256 * 4);
  float* ystate= (float*)alloc((size_t)256 * 256 * 4);
  float* ypstate=(float*)alloc((size_t)256 * 256 * 4);
  float* zstate= (float*)alloc((size_t)256 * 256 * 4);
  uint32_t* yexch  = (uint32_t*)alloc((size_t)2 * 16 * 1024 * 16);
  uint32_t* yexch2 = (uint32_t*)alloc((size_t)2 * 16 * 1024 * 16);
  uint32_t* zexch  = (uint32_t*)alloc((size_t)2 * 16 * 1024 * 16);
  uint32_t* zexch2 = (uint32_t*)alloc((size_t)2 * 16 * 1024 * 16);
  size_t fixed = off;
  size_t per_slot = (size_t)131072 * 2 + 65536 * 2 + 65536 * 2 + 65536 * 2;
  size_t per_t = 10 * per_slot + (size_t)10 * 196608 * 2 + 131072 + 131072 + 524288;
  int Tc = 1;
  if (ws_size > fixed + per_t + per_slot) {
    size_t n = (ws_size - fixed - per_slot) / per_t;
    Tc = (n > 128) ? 128 : (int)n;
  }
  if (Tc < 1) Tc = 1;
  int maxslots = Tc * 10 + 1;
  u16* Apack   = (u16*)alloc((size_t)maxslots * 131072 * 2);
  u16* Sny     = (u16*)alloc((size_t)maxslots * 65536 * 2);
  u16* Snz     = (u16*)alloc((size_t)maxslots * 65536 * 2);
  u16* nyA     = (u16*)alloc((size_t)maxslots * 65536 * 2);
  u16* HNpack  = (u16*)alloc((size_t)(Tc * 10) * 196608 * 2);
  u16* inpPack = (u16*)alloc((size_t)Tc * 16 * 8 * 512 * 2);
  u16* XIpack  = (u16*)alloc((size_t)Tc * 524288);
  u16* Ypack   = (u16*)alloc((size_t)Tc * 16 * 8 * 512 * 2);

  (void)hipFuncSetAttribute((const void*)k_recur, hipFuncAttributeMaxDynamicSharedMemorySize,
                            R_LDS_BYTES);

  k_prep<<<1024, 256, 0, stream>>>(W_i, W_c, b_i, b_c, Wic, bip);
  k_bias<<<4, 256, 0, stream>>>(b_i, bip, b_h, biasD0, biasDn);
  k_packw<<<(112 * 8 * 64) / 256, 256, 0, stream>>>(Wic, 1024, W_h, Epack, 1792, 256);
  k_packw<<<(64 * 8 * 64) / 256, 256, 0, stream>>>(W_i, 1024, (const float*)nullptr, Wipack, 1024, 256);
  k_packw<<<(16 * 8 * 64) / 256, 256, 0, stream>>>(W_z, 256, (const float*)nullptr, Wzpack, 256, 256);
  k_packw<<<(16 * 8 * 64) / 256, 256, 0, stream>>>(W_c, 256, (const float*)nullptr, Wcpack, 256, 256);
  k_packw<<<(32 * 16 * 64) / 256, 256, 0, stream>>>(W_s, 512, (const float*)nullptr, Wspack, 512, 512);
  k_packe2<<<128, 256, 0, stream>>>(Wic, W_h, E2pack);

  for (int t0 = 0; t0 < 128; t0 += Tc) {
    int Tcc = (128 - t0 < Tc) ? (128 - t0) : Tc;
    int nsteps = Tcc * 10;
    int slots = nsteps + 1;
    k_gen<<<slots * 128, 1024, 0, stream>>>(Apack, t0 * 10 - 1);
    dim3 g2(slots, 4);
    k_sgemm<<<g2, 512, 0, stream>>>(Apack, Wspack, b_s, Sny, Snz, nyA);
    dim3 g3(nsteps, 6);
    k_hn<<<g3, 512, 0, stream>>>(nyA, Epack, HNpack, t0);
    int totalA = Tcc * 16 * 8 * 64;
    k_packa<<<(totalA + 255) / 256, 256, 0, stream>>>(input, t0, Tcc, inpPack);
    dim3 gx(Tcc, 8);
    k_xi<<<gx, 512, 0, stream>>>(inpPack, Wipack, XIpack);
    k_recur<<<64, 512, R_LDS_BYTES, stream>>>(dt, Epack, Wzpack, E2pack, HNpack, XIpack,
                                              biasD0, biasDn, b_z, W_dt, b_dt, Sny, Snz,
                                              Ypack, ystate, ypstate, zstate,
                                              yexch, yexch2, zexch, zexch2, t0, Tcc);
    dim3 ge(Tcc, 4);
    k_out<<<ge, 512, 0, stream>>>(Ypack, Wcpack, b_c, out, t0);
  }
}

// Round 15
// 7331.537 us; speedup vs baseline: 1.2081x; 1.2081x over previous
//
#include <hip/hip_runtime.h>
#include <stdint.h>

// ---------------------------------------------------------------------------
// LEM-style noisy RNN. T=128 x DIV=10 sequential steps, B=256, H=256.
// Round 15: transport stripped to minimum. Single L3 payload path (sc0 sc1):
// publish = one 16B {data,seq,data,seq} store; poll = one paired L3 load per
// iteration (r13's dual L2+L3 probe wasted an L2 RT per miss; r14 proved the
// L2 path can never win: consumer L2 caches the stale line forever).
// Keeps: direct register publish (C/D order), consumer scatterPair (4x u32),
// XI=Wi@x + HN=Wh@ny precompute, E2=Wic+Wh in LDS, Wz in regs, 16 groups x
// 4 WGs (Y0,Y1,Z0,Z1), in-register phase fusion.
// ---------------------------------------------------------------------------

typedef __attribute__((ext_vector_type(8))) short bf16x8_t;
typedef __attribute__((ext_vector_type(4))) float f32x4_t;
typedef __attribute__((ext_vector_type(4))) unsigned int u32x4_t;
typedef unsigned short u16;

#define R_LDS_BYTES 147712

__device__ __forceinline__ float bf2f(u16 b) {
  union { uint32_t u; float f; } v; v.u = ((uint32_t)b) << 16; return v.f;
}
__device__ __forceinline__ u16 f2bf(float f) {
  union { float f; uint32_t u; } v; v.f = f;
  uint32_t x = v.u;
  return (u16)((x + 0x7FFFu + ((x >> 16) & 1u)) >> 16);   // RNE
}
__device__ __forceinline__ f32x4_t mfma16(bf16x8_t a, bf16x8_t b, f32x4_t c) {
  return __builtin_amdgcn_mfma_f32_16x16x32_bf16(a, b, c, 0, 0, 0);
}
__device__ __forceinline__ float sigm(float x) { return 1.0f / (1.0f + __expf(-x)); }
__device__ __forceinline__ float tanh_f(float x) {
  float t = __expf(-2.0f * fabsf(x));
  float r = (1.0f - t) / (1.0f + t);
  return x < 0.0f ? -r : r;
}

// A-frag slot for (k in [0,256), row m in [0,16))
__device__ __forceinline__ int fslot(int k, int m) {
  return ((k >> 5) * 512) + (((((k & 15) >> 2) << 4) | m) << 3) +
         ((k & 3) | (((k >> 4) & 1) << 2));
}
// MFMA 16x16x32 bf16 A-frag K-position for lane l, elem e
__device__ __forceinline__ int fragK(int l, int e) {
  return ((l >> 4) << 2) + (e & 3) + ((e >> 2) << 4);
}

// ---- single-path L3-coherent transport (sc0 sc1 = bypass L1+L2) ----
__device__ __forceinline__ void publish(uint32_t* p3, uint32_t w0, uint32_t w1, uint32_t seq) {
  u32x4_t pay; pay.x = w0; pay.y = seq; pay.z = w1; pay.w = seq;
  asm volatile("global_store_dwordx4 %0, %1, off sc0 sc1" :: "v"(p3), "v"(pay) : "memory");
}
__device__ __forceinline__ void pollpair(const uint32_t* p, uint32_t seq,
                                         u32x4_t* a, u32x4_t* b) {
  while (true) {
    u32x4_t x, y;
    asm volatile("global_load_dwordx4 %0, %2, off sc0 sc1\n\t"
                 "global_load_dwordx4 %1, %3, off sc0 sc1\n\t"
                 "s_waitcnt vmcnt(0)"
                 : "=&v"(x), "=&v"(y) : "v"(p), "v"(p + 4) : "memory");
    if (x.y == seq && x.w == seq && y.y == seq && y.w == seq) { *a = x; *b = y; return; }
    __builtin_amdgcn_s_sleep(1);
  }
}
// scatter a PAIR of C/D-order payload slots (j even: j, j+1) as 4 u32 writes.
// fslot(col+1,m) == fslot(col,m)+1 for even col -> adjacent u16s.
__device__ __forceinline__ void scatterPair(u16* dst, int j, u32x4_t pa, u32x4_t pb) {
  int wvp = (j >> 6) & 7, lp = j & 63, hf = j >> 9;
  int colp = hf * 128 + wvp * 16 + (lp & 15);   // even
  int mb = 4 * (lp >> 4);
  int base = fslot(colp, mb);                   // even
  uint32_t* d = (uint32_t*)(dst + base);
  d[0]  = (pa.x & 0xffffu) | ((pb.x & 0xffffu) << 16);
  d[4]  = (pa.x >> 16)     | (pb.x & 0xffff0000u);
  d[8]  = (pa.z & 0xffffu) | ((pb.z & 0xffffu) << 16);
  d[12] = (pa.z >> 16)     | (pb.z & 0xffff0000u);
}

// ---- JAX threefry2x32 (20 rounds) ----
__device__ __forceinline__ void threefry(uint32_t k0, uint32_t k1, uint32_t x0, uint32_t x1,
                                         uint32_t* o0, uint32_t* o1) {
  uint32_t ks2 = k0 ^ k1 ^ 0x1BD11BDAu;
  x0 += k0; x1 += k1;
#define TFR(rot) { x0 += x1; x1 = (x1 << rot) | (x1 >> (32 - rot)); x1 ^= x0; }
  TFR(13) TFR(15) TFR(26) TFR(6)   x0 += k1;  x1 += ks2 + 1u;
  TFR(17) TFR(29) TFR(16) TFR(24)  x0 += ks2; x1 += k0 + 2u;
  TFR(13) TFR(15) TFR(26) TFR(6)   x0 += k0;  x1 += k1 + 3u;
  TFR(17) TFR(29) TFR(16) TFR(24)  x0 += k1;  x1 += ks2 + 4u;
  TFR(13) TFR(15) TFR(26) TFR(6)   x0 += ks2; x1 += k0 + 5u;
#undef TFR
  *o0 = x0; *o1 = x1;
}

// bits -> N(0,1), matches jax.random.normal f32 (XLA erfinv poly)
__device__ __forceinline__ float bits2normal(uint32_t bits) {
  union { uint32_t u; float f; } cv; cv.u = 0x3F800000u | (bits >> 9);
  float f = cv.f - 1.0f;
  float u = fmaf(f, 2.0f, -0.99999994f);
  u = fmaxf(u, -0.99999994f);
  float w = -log1pf(-u * u);
  float p;
  if (w < 5.0f) {
    w = w - 2.5f;
    p = 2.81022636e-08f;
    p = fmaf(p, w, 3.43273939e-07f);
    p = fmaf(p, w, -3.5233877e-06f);
    p = fmaf(p, w, -4.39150654e-06f);
    p = fmaf(p, w, 0.00021858087f);
    p = fmaf(p, w, -0.00125372503f);
    p = fmaf(p, w, -0.00417768164f);
    p = fmaf(p, w, 0.246640727f);
    p = fmaf(p, w, 1.50140941f);
  } else {
    w = sqrtf(w) - 3.0f;
    p = -0.000200214257f;
    p = fmaf(p, w, 0.000100950558f);
    p = fmaf(p, w, 0.00134934322f);
    p = fmaf(p, w, -0.00367342844f);
    p = fmaf(p, w, 0.00573950773f);
    p = fmaf(p, w, -0.0076224613f);
    p = fmaf(p, w, 0.00943887047f);
    p = fmaf(p, w, 1.00167406f);
    p = fmaf(p, w, 2.83297682f);
  }
  return 1.41421354f * p * u;
}

// ---------------------------------------------------------------------------
__global__ void k_prep(const float* __restrict__ W_i, const float* __restrict__ W_c,
                       const float* __restrict__ b_i, const float* __restrict__ b_c,
                       float* __restrict__ Wic, float* __restrict__ bip) {
  __shared__ float wi[256];
  __shared__ float red[256];
  int o = blockIdx.x; int tid = threadIdx.x;
  wi[tid] = W_i[o * 256 + tid];
  __syncthreads();
  float acc = 0.f;
  for (int j = 0; j < 256; ++j) acc = fmaf(wi[j], W_c[j * 256 + tid], acc);
  Wic[(size_t)o * 256 + tid] = acc;
  red[tid] = wi[tid] * b_c[tid];
  __syncthreads();
  for (int s = 128; s > 0; s >>= 1) { if (tid < s) red[tid] += red[tid + s]; __syncthreads(); }
  if (tid == 0) bip[o] = b_i[o] + red[0];
}

__global__ void k_bias(const float* __restrict__ b_i, const float* __restrict__ bip,
                       const float* __restrict__ b_h,
                       float* __restrict__ biasD0, float* __restrict__ biasDn) {
  int c = blockIdx.x * 256 + threadIdx.x;
  float bh = (c < 512) ? b_h[c] : (c >= 768 ? b_h[c - 256] : 0.f);
  biasD0[c] = b_i[c] + bh;
  biasDn[c] = bip[c] + bh;
}

__global__ void k_packw(const float* __restrict__ srcA, int rowsA, const float* __restrict__ srcB,
                        u16* __restrict__ dst, int O, int K) {
  int t = blockIdx.x * blockDim.x + threadIdx.x;
  int KK = K >> 5;
  int total = (O >> 4) * KK * 64;
  if (t >= total) return;
  int l = t & 63; int kk = (t >> 6) % KK; int to = t / (64 * KK);
  int n = (to << 4) | (l & 15);
  int kb = (kk << 5) + ((l >> 4) << 2);
  const float* src = (n < rowsA) ? (srcA + (size_t)n * K) : (srcB + (size_t)(n - rowsA) * K);
  u16 out[8];
#pragma unroll
  for (int e = 0; e < 8; ++e) out[e] = f2bf(src[kb + (e & 3) + ((e >> 2) << 4)]);
  *reinterpret_cast<uint4*>(dst + (size_t)t * 8) = *reinterpret_cast<const uint4*>(out);
}

// E2 = Wic + Wh aligned (cols 0..511 -> Wh[c], 768..1023 -> Wh[c-256]), 64 tiles
__global__ void k_packe2(const float* __restrict__ Wic, const float* __restrict__ Wh,
                         u16* __restrict__ dst) {
  int t = blockIdx.x * blockDim.x + threadIdx.x;   // 64*8*64 = 32768
  int l = t & 63; int kk = (t >> 6) & 7; int to = t >> 9;
  int n = (to << 4) | (l & 15);
  int kb = (kk << 5) + ((l >> 4) << 2);
  u16 out[8];
#pragma unroll
  for (int e = 0; e < 8; ++e) {
    int k = kb + (e & 3) + ((e >> 2) << 4);
    float v = Wic[(size_t)n * 256 + k];
    if (n < 512) v += Wh[(size_t)n * 256 + k];
    else if (n >= 768) v += Wh[(size_t)(n - 256) * 256 + k];
    out[e] = f2bf(v);
  }
  *reinterpret_cast<uint4*>(dst + (size_t)t * 8) = *reinterpret_cast<const uint4*>(out);
}

__global__ void k_packa(const float* __restrict__ inp, int t0, int Tcc, u16* __restrict__ dst) {
  int t = blockIdx.x * blockDim.x + threadIdx.x;
  int total = Tcc * 16 * 8 * 64;
  if (t >= total) return;
  int l = t & 63; int kk = (t >> 6) & 7; int mt = (t >> 9) & 15; int tl = t >> 13;
  int b = (mt << 4) | (l & 15);
  int kb = (kk << 5) + ((l >> 4) << 2);
  const float* src = inp + ((size_t)(t0 + tl) * 256 + b) * 256;
  u16 out[8];
#pragma unroll
  for (int e = 0; e < 8; ++e) out[e] = f2bf(src[kb + (e & 3) + ((e >> 2) << 4)]);
  *reinterpret_cast<uint4*>(dst + (size_t)t * 8) = *reinterpret_cast<const uint4*>(out);
}

// noise gen; slot sl = global noise step gstep0+sl (gstep0 = t0*10-1)
__global__ void k_gen(u16* __restrict__ Apack, int gstep0) {
  int sl = blockIdx.x >> 7;
  int tb = (blockIdx.x & 127) * 1024 + threadIdx.x;   // [0, 131072)
  __shared__ uint32_t kf[2];
  if (threadIdx.x == 0) {
    uint32_t o0, o1;
    threefry(0u, 1234u, 0u, (uint32_t)(gstep0 + sl), &o0, &o1);
    kf[0] = o0; kf[1] = o1;
  }
  __syncthreads();
  int e = tb & 7; int l = (tb >> 3) & 63; int kk = (tb >> 9) & 15; int mt = tb >> 13;
  int b = (mt << 4) | (l & 15);
  int c = (kk << 5) + fragK(l, e);
  uint32_t i = (uint32_t)(b * 512 + c);
  uint32_t o0, o1;
  threefry(kf[0], kf[1], 0u, i, &o0, &o1);
  Apack[(size_t)sl * 131072 + tb] = f2bf(bits2normal(o0 ^ o1));
}

// S = tanh(noise @ Ws^T + b_s) -> Sny/Snz (per (g,half), C/D-row-mapped thread
// order), and nyA (n<256 in A-frag layout, input for k_hn).
__global__ __launch_bounds__(512) void k_sgemm(const u16* __restrict__ Apack,
                                               const u16* __restrict__ Wspack,
                                               const float* __restrict__ b_s,
                                               u16* __restrict__ Sny, u16* __restrict__ Snz,
                                               u16* __restrict__ nyA) {
  int sl = blockIdx.x; int nq = blockIdx.y;
  int l = threadIdx.x & 63; int wv = threadIdx.x >> 6;
  const u16* Ab = Apack + (size_t)sl * 131072;
#pragma unroll 1
  for (int mtl = 0; mtl < 2; ++mtl) {
    int mt = 2 * wv + mtl;
    bf16x8_t af[16];
#pragma unroll
    for (int kk = 0; kk < 16; ++kk)
      af[kk] = *reinterpret_cast<const bf16x8_t*>(Ab + ((size_t)(mt * 16 + kk) * 64 + l) * 8);
#pragma unroll 1
    for (int ntl = 0; ntl < 8; ++ntl) {
      int nt = nq * 8 + ntl;
      f32x4_t acc = {0.f, 0.f, 0.f, 0.f};
#pragma unroll
      for (int kk = 0; kk < 16; ++kk) {
        bf16x8_t bfr = *reinterpret_cast<const bf16x8_t*>(Wspack + ((size_t)(nt * 16 + kk) * 64 + l) * 8);
        acc = mfma16(af[kk], bfr, acc);
      }
      int n = (nt << 4) | (l & 15);
      float bs = b_s[n];
#pragma unroll
      for (int r = 0; r < 4; ++r) {
        int m = (mt << 4) + ((l >> 4) << 2) + r;
        u16 v = f2bf(tanh_f(acc[r] + bs));
        int g = m >> 4, row = m & 15;
        if (n >= 256) {
          int h = n - 256; int hz = h >> 7;
          int tidc = ((h >> 4) & 7) * 64 + ((row >> 2) << 4) + (h & 15);
          Snz[((((size_t)sl * 16 + g) * 2 + hz) * 512 + tidc) * 4 + (row & 3)] = v;
        } else {
          int hy = n >> 7;
          int tidc = ((n >> 4) & 7) * 64 + ((row >> 2) << 4) + (n & 15);
          Sny[((((size_t)sl * 16 + g) * 2 + hy) * 512 + tidc) * 4 + (row & 3)] = v;
          int kk2 = n >> 5;
          int la = (((n & 15) >> 2) << 4) | row;
          int ea = (n & 3) | (((n >> 4) & 1) << 2);
          nyA[(((size_t)sl * 16 + g) * 8 + kk2) * 512 + la * 8 + ea] = v;
        }
      }
    }
  }
}

// HN[j] = Wh @ ny(slot j), C/D-frag layout (bf16), 48 col-tiles.
__global__ __launch_bounds__(512) void k_hn(const u16* __restrict__ nyA,
                                            const u16* __restrict__ Epack,
                                            u16* __restrict__ HNpack, int t0) {
  int j = blockIdx.x; int nq = blockIdx.y;
  int l = threadIdx.x & 63; int wv = threadIdx.x >> 6;
  int nt = nq * 8 + wv;                      // [0,48)
  if (j == 0 && t0 == 0) {
    uint2 z = {0u, 0u};
#pragma unroll 1
    for (int mt = 0; mt < 16; ++mt)
      *reinterpret_cast<uint2*>(&HNpack[(((size_t)j * 16 + mt) * 48 + nt) * 256 + l * 4]) = z;
    return;
  }
  bf16x8_t bf[8];
  const u16* bp = Epack + (size_t)(64 + nt) * 4096 + (size_t)l * 8;
#pragma unroll
  for (int kk = 0; kk < 8; ++kk)
    bf[kk] = *reinterpret_cast<const bf16x8_t*>(bp + kk * 512);
#pragma unroll 1
  for (int mt = 0; mt < 16; ++mt) {
    const u16* ap = nyA + (((size_t)j * 16 + mt) * 8) * 512 + (size_t)l * 8;
    f32x4_t acc = {0.f, 0.f, 0.f, 0.f};
#pragma unroll
    for (int kk = 0; kk < 8; ++kk)
      acc = mfma16(*reinterpret_cast<const bf16x8_t*>(ap + kk * 512), bf[kk], acc);
    union { u16 h[4]; uint2 v; } o;
#pragma unroll
    for (int r = 0; r < 4; ++r) o.h[r] = f2bf(acc[r]);
    *reinterpret_cast<uint2*>(&HNpack[(((size_t)j * 16 + mt) * 48 + nt) * 256 + l * 4]) = o.v;
  }
}

// XI[tl][g] = x @ Wi^T, C/D-frag layout (bf16), 64 col-tiles.
__global__ __launch_bounds__(512) void k_xi(const u16* __restrict__ inpPack,
                                            const u16* __restrict__ Wipack,
                                            u16* __restrict__ XIpack) {
  int tl = blockIdx.x; int nb = blockIdx.y;
  int l = threadIdx.x & 63; int wv = threadIdx.x >> 6;
  int nt = nb * 8 + wv;                      // [0,64)
  bf16x8_t bf[8];
  const u16* bp = Wipack + (size_t)nt * 4096 + (size_t)l * 8;
#pragma unroll
  for (int kk = 0; kk < 8; ++kk)
    bf[kk] = *reinterpret_cast<const bf16x8_t*>(bp + kk * 512);
#pragma unroll 1
  for (int g = 0; g < 16; ++g) {
    const u16* ap = inpPack + (size_t)(tl * 16 + g) * 4096 + (size_t)l * 8;
    f32x4_t acc = {0.f, 0.f, 0.f, 0.f};
#pragma unroll
    for (int kk = 0; kk < 8; ++kk)
      acc = mfma16(*reinterpret_cast<const bf16x8_t*>(ap + kk * 512), bf[kk], acc);
    union { u16 h[4]; uint2 v; } o;
#pragma unroll
    for (int r = 0; r < 4; ++r) o.h[r] = f2bf(acc[r]);
    *reinterpret_cast<uint2*>(&XIpack[(((size_t)tl * 16 + g) * 64 + nt) * 256 + l * 4]) = o.v;
  }
}

// ---------------------------------------------------------------------------
// Recurrence, 64 WGs x 512. wgid = role*16 + g. role 0/1 = Y(hy), 2/3 = Z(hz).
__global__ __launch_bounds__(512, 2) void k_recur(
    const float* __restrict__ dt,
    const u16* __restrict__ Epack, const u16* __restrict__ Wzpack,
    const u16* __restrict__ E2pack, const u16* __restrict__ HNpack,
    const u16* __restrict__ XIpack,
    const float* __restrict__ biasD0, const float* __restrict__ biasDn,
    const float* __restrict__ b_z, const float* __restrict__ W_dt, const float* __restrict__ b_dt,
    const u16* __restrict__ Sny, const u16* __restrict__ Snz,
    u16* __restrict__ Ypack, float* __restrict__ ystate, float* __restrict__ ypstate,
    float* __restrict__ zstate,
    uint32_t* __restrict__ yexch, uint32_t* __restrict__ zexch,
    int t0, int Tcc)
{
  extern __shared__ char lds_raw[];
  u16* wlds = (u16*)lds_raw;            // 65536 u16 (128KB): E2 tiles
  u16* buf  = wlds + 65536;             // 8192 u16: Z: y-frag dbuf; Y: [0]=y frags, [4096]=z frags
  float* sc  = (float*)(buf + 8192);    // 48
  float* scP = sc + 48;                 // 16

  const int wgid = blockIdx.x;
  const int g = wgid & 15;
  const int role = wgid >> 4;
  const bool isY = role < 2;
  const int half = role & 1;
  const int tid = threadIdx.x;
  const int l = tid & 63;
  const int wv = tid >> 6;
  const int nsteps = Tcc * 10;
  const int m2b = 4 * (l >> 4);
  const int col = half * 128 + wv * 16 + (l & 15);
  const uint32_t gb = (uint32_t)(t0 * 10);

  int wiT0, whT0, hnT0, wiT1, whT1 = -1, hnT1 = -1;
  if (isY) {
    wiT0 = half * 8 + wv;       whT0 = 64 + wiT0;  hnT0 = wiT0;
    wiT1 = 32 + half * 8 + wv;
  } else {
    wiT0 = 16 + half * 8 + wv;  whT0 = 64 + wiT0;  hnT0 = wiT0;
    wiT1 = 48 + half * 8 + wv;  whT1 = 96 + half * 8 + wv;  hnT1 = 32 + half * 8 + wv;
  }
  float b0d0 = biasD0[wiT0 * 16 + (l & 15)], b0dn = biasDn[wiT0 * 16 + (l & 15)];
  float b1d0 = biasD0[wiT1 * 16 + (l & 15)], b1dn = biasDn[wiT1 * 16 + (l & 15)];

  // ---- preload E2 weight tiles into LDS ----
  for (int i = tid; i < 8192; i += 512) {
    int t = i >> 9; int o = (i & 511) << 3;
    int gt;
    if (isY) gt = (t < 8) ? (half * 8 + t) : (32 + half * 8 + (t - 8));
    else     gt = (t < 8) ? (16 + half * 8 + t) : (48 + half * 8 + (t - 8));
    *reinterpret_cast<uint4*>(wlds + t * 4096 + o) =
        *reinterpret_cast<const uint4*>(E2pack + (size_t)gt * 4096 + o);
  }

  float zc[4], yc[4], ylast[4];
  bf16x8_t wzf[8];
  float bzr = 0.f;
  float wdt0 = W_dt[0], wdt1 = W_dt[1], bdt0 = b_dt[0], bdt1 = b_dt[1];

  if (isY) {
    bzr = b_z[col];
#pragma unroll
    for (int kk = 0; kk < 8; ++kk)
      wzf[kk] = *reinterpret_cast<const bf16x8_t*>(
          Wzpack + (size_t)(half * 8 + wv) * 4096 + (size_t)kk * 512 + (size_t)l * 8);
    u16 v[4];
#pragma unroll
    for (int r = 0; r < 4; ++r) {
      int m2 = m2b + r;
      yc[r] = (t0 == 0) ? 0.f : ystate[(size_t)(g * 16 + m2) * 256 + col];
      ylast[r] = 0.f;
      float vv = (t0 == 0) ? 0.f : ypstate[(size_t)(g * 16 + m2) * 256 + col];
      v[r] = f2bf(vv);
    }
    int base = fslot(col, m2b);
    buf[base] = v[0]; buf[base + 8] = v[1]; buf[base + 16] = v[2]; buf[base + 24] = v[3];
    uint32_t w0 = (uint32_t)v[0] | ((uint32_t)v[1] << 16);
    uint32_t w1 = (uint32_t)v[2] | ((uint32_t)v[3] << 16);
    publish(yexch + ((size_t)g * 1024 + half * 512 + tid) * 4, w0, w1, gb + 1u);
  } else {
#pragma unroll
    for (int r = 0; r < 4; ++r)
      zc[r] = (t0 == 0) ? 0.f : zstate[(size_t)(g * 16 + m2b + r) * 256 + col];
  }

  if (!isY) {
    // =============== Z loop: 1 barrier/step ===============
    for (int s = 0; s < nsteps; ++s) {
      int d = s % 10;
      uint2 nsv = *reinterpret_cast<const uint2*>(
          Snz + ((((size_t)(s + 1) * 16 + g) * 2 + half) * 512 + tid) * 4);
      size_t HNs = ((size_t)s * 16 + g) * 48;
      uint2 hv0 = *reinterpret_cast<const uint2*>(HNpack + (HNs + hnT0) * 256 + l * 4);
      uint2 hv1 = *reinterpret_cast<const uint2*>(HNpack + (HNs + hnT1) * 256 + l * 4);
      uint2 xi0 = {0u, 0u}, xi1 = {0u, 0u};
      if (d == 0) {
        int tl = s / 10;
        size_t XIs = ((size_t)tl * 16 + g) * 64;
        xi0 = *reinterpret_cast<const uint2*>(XIpack + (XIs + wiT0) * 256 + l * 4);
        xi1 = *reinterpret_cast<const uint2*>(XIpack + (XIs + wiT1) * 256 + l * 4);
        if (tid < 16) {
          float dl = dt[(size_t)(t0 + tl) * 256 + g * 16 + tid] * 0.1f;
          sc[tid] = dl;
          sc[16 + tid] = sigm(fmaf(dl, wdt0, bdt0));
          sc[32 + tid] = sigm(fmaf(dl, wdt1, bdt1));
          int tp = t0 + tl - 1; if (tp < 0) tp = 0;
          scP[tid] = dt[(size_t)tp * 256 + g * 16 + tid] * 0.1f;
        }
      }
      uint32_t seq = gb + (uint32_t)s + 1u;
      // poll full y; paired scatter into parity buffer
      size_t bo = (((size_t)(s & 1) * 16 + g) * 1024 + 2 * tid) * 4;
      u32x4_t pa, pb;
      pollpair(yexch + bo, seq, &pa, &pb);
      u16* yb = buf + (s & 1) * 4096;
      scatterPair(yb, 2 * tid, pa, pb);
      __syncthreads();
      // ---- A ----
      bf16x8_t ay[8];
#pragma unroll
      for (int kk = 0; kk < 8; ++kk)
        ay[kk] = *reinterpret_cast<const bf16x8_t*>(yb + kk * 512 + l * 8);
      float scv[4];
#pragma unroll
      for (int r = 0; r < 4; ++r) scv[r] = (d == 0 ? scP[m2b + r] : sc[m2b + r]);
      f32x4_t a0 = {0.f, 0.f, 0.f, 0.f}, a1 = {0.f, 0.f, 0.f, 0.f};
      if (d == 0) {
        const u16* hp0 = Epack + (size_t)whT0 * 4096 + (size_t)l * 8;
        const u16* hp1 = Epack + (size_t)whT1 * 4096 + (size_t)l * 8;
#pragma unroll
        for (int kk = 0; kk < 8; ++kk)
          a0 = mfma16(ay[kk], *reinterpret_cast<const bf16x8_t*>(hp0 + kk * 512), a0);
#pragma unroll
        for (int kk = 0; kk < 8; ++kk)
          a1 = mfma16(ay[kk], *reinterpret_cast<const bf16x8_t*>(hp1 + kk * 512), a1);
      } else {
        const u16* w0p = wlds + wv * 4096 + l * 8;
        const u16* w1p = wlds + (8 + wv) * 4096 + l * 8;
#pragma unroll
        for (int kk = 0; kk < 8; ++kk)
          a0 = mfma16(ay[kk], *reinterpret_cast<const bf16x8_t*>(w0p + kk * 512), a0);
#pragma unroll
        for (int kk = 0; kk < 8; ++kk)
          a1 = mfma16(ay[kk], *reinterpret_cast<const bf16x8_t*>(w1p + kk * 512), a1);
      }
      const u16* h0 = (const u16*)&hv0; const u16* h1 = (const u16*)&hv1;
      const u16* x0 = (const u16*)&xi0; const u16* x1 = (const u16*)&xi1;
      // ---- B: z update, publish direct ----
      const u16* nzp = (const u16*)&nsv;
      u16 zv[4];
#pragma unroll
      for (int r = 0; r < 4; ++r) {
        int m2 = m2b + r;
        float r0 = a0[r] + (d == 0 ? (b0d0 + bf2f(x0[r])) : b0dn) + scv[r] * bf2f(h0[r]);
        float r1 = a1[r] + (d == 0 ? (b1d0 + bf2f(x1[r])) : b1dn) + scv[r] * bf2f(h1[r]);
        float ms = sc[32 + m2] * sigm(r0);
        float zn = (1.0f - ms) * zc[r] + ms * tanh_f(r1);
        zv[r] = f2bf(zn);
        zc[r] = fmaf(bf2f(nzp[r]), sc[m2], zn);
      }
      uint32_t w0z = (uint32_t)zv[0] | ((uint32_t)zv[1] << 16);
      uint32_t w1z = (uint32_t)zv[2] | ((uint32_t)zv[3] << 16);
      publish(zexch + (((size_t)(s & 1) * 16 + g) * 1024 + half * 512 + tid) * 4, w0z, w1z, seq);
    }
#pragma unroll
    for (int r = 0; r < 4; ++r)
      zstate[(size_t)(g * 16 + m2b + r) * 256 + col] = zc[r];
  } else {
    // =============== Y loop: 2 barriers/step ===============
    for (int s = 0; s < nsteps; ++s) {
      int d = s % 10, tl = s / 10;
      uint2 nsv = *reinterpret_cast<const uint2*>(
          Sny + ((((size_t)(s + 1) * 16 + g) * 2 + half) * 512 + tid) * 4);
      size_t HNs = ((size_t)s * 16 + g) * 48;
      uint2 hv0 = *reinterpret_cast<const uint2*>(HNpack + (HNs + hnT0) * 256 + l * 4);
      uint2 xi0 = {0u, 0u}, xi1 = {0u, 0u};
      if (d == 0) {
        size_t XIs = ((size_t)tl * 16 + g) * 64;
        xi0 = *reinterpret_cast<const uint2*>(XIpack + (XIs + wiT0) * 256 + l * 4);
        xi1 = *reinterpret_cast<const uint2*>(XIpack + (XIs + wiT1) * 256 + l * 4);
        if (tid < 16) {
          float dl = dt[(size_t)(t0 + tl) * 256 + g * 16 + tid] * 0.1f;
          sc[tid] = dl;
          sc[16 + tid] = sigm(fmaf(dl, wdt0, bdt0));
          sc[32 + tid] = sigm(fmaf(dl, wdt1, bdt1));
          int tp = t0 + tl - 1; if (tp < 0) tp = 0;
          scP[tid] = dt[(size_t)tp * 256 + g * 16 + tid] * 0.1f;
        }
      }
      uint32_t seq = gb + (uint32_t)s + 1u;
      // poll other y half (self half written during previous C): 256 threads x pair
      if (tid < 256) {
        int j = (1 ^ half) * 512 + 2 * tid;
        size_t bo = (((size_t)(s & 1) * 16 + g) * 1024 + j) * 4;
        u32x4_t pa, pb;
        pollpair(yexch + bo, seq, &pa, &pb);
        scatterPair(buf, j, pa, pb);
      }
      __syncthreads();                                  // BAR_1
      // ---- A ----
      f32x4_t r0v, r1v;
      {
        bf16x8_t ay[8];
#pragma unroll
        for (int kk = 0; kk < 8; ++kk)
          ay[kk] = *reinterpret_cast<const bf16x8_t*>(buf + kk * 512 + l * 8);
        float scv[4];
#pragma unroll
        for (int r = 0; r < 4; ++r) scv[r] = (d == 0 ? scP[m2b + r] : sc[m2b + r]);
        f32x4_t a0 = {0.f, 0.f, 0.f, 0.f}, a1 = {0.f, 0.f, 0.f, 0.f};
        if (d == 0) {
          const u16* hp0 = Epack + (size_t)whT0 * 4096 + (size_t)l * 8;
#pragma unroll
          for (int kk = 0; kk < 8; ++kk)
            a0 = mfma16(ay[kk], *reinterpret_cast<const bf16x8_t*>(hp0 + kk * 512), a0);
        } else {
          const u16* w0p = wlds + wv * 4096 + l * 8;
          const u16* w1p = wlds + (8 + wv) * 4096 + l * 8;
#pragma unroll
          for (int kk = 0; kk < 8; ++kk)
            a0 = mfma16(ay[kk], *reinterpret_cast<const bf16x8_t*>(w0p + kk * 512), a0);
#pragma unroll
          for (int kk = 0; kk < 8; ++kk)
            a1 = mfma16(ay[kk], *reinterpret_cast<const bf16x8_t*>(w1p + kk * 512), a1);
        }
        const u16* h0 = (const u16*)&hv0;
        const u16* x0 = (const u16*)&xi0; const u16* x1 = (const u16*)&xi1;
#pragma unroll
        for (int r = 0; r < 4; ++r) {
          r0v[r] = a0[r] + (d == 0 ? (b0d0 + bf2f(x0[r])) : b0dn) + scv[r] * bf2f(h0[r]);
          r1v[r] = (d == 0) ? (b1d0 + bf2f(x1[r])) : (a1[r] + b1dn);
        }
      }
      // poll z (full), paired scatter
      {
        size_t bo = (((size_t)(s & 1) * 16 + g) * 1024 + 2 * tid) * 4;
        u32x4_t qa, qb;
        pollpair(zexch + bo, seq, &qa, &qb);
        scatterPair(buf + 4096, 2 * tid, qa, qb);
      }
      __syncthreads();                                  // BAR_2
      // ---- C ----
      bf16x8_t zfr[8];
#pragma unroll
      for (int kk = 0; kk < 8; ++kk)
        zfr[kk] = *reinterpret_cast<const bf16x8_t*>(buf + 4096 + kk * 512 + l * 8);
      f32x4_t acc = {0.f, 0.f, 0.f, 0.f};
#pragma unroll
      for (int kk = 0; kk < 8; ++kk) acc = mfma16(zfr[kk], wzf[kk], acc);
      const u16* nyp = (const u16*)&nsv;
      u16 yv[4], pv[4];
      int base = fslot(col, m2b);
#pragma unroll
      for (int r = 0; r < 4; ++r) {
        int m2 = m2b + r;
        float u = acc[r] + bzr + r1v[r];
        float msb = sc[16 + m2] * sigm(r0v[r]);
        float yn = (1.0f - msb) * yc[r] + msb * tanh_f(u);
        float ypn = fmaf(bf2f(nyp[r]), sc[m2], yn);
        yc[r] = ypn; ylast[r] = yn;
        yv[r] = f2bf(yn); pv[r] = f2bf(ypn);
        buf[base + 8 * r] = yv[r];                      // self-half y(s+1)
      }
      uint32_t wy0 = (uint32_t)yv[0] | ((uint32_t)yv[1] << 16);
      uint32_t wy1 = (uint32_t)yv[2] | ((uint32_t)yv[3] << 16);
      publish(yexch + (((size_t)((s + 1) & 1) * 16 + g) * 1024 + half * 512 + tid) * 4,
              wy0, wy1, gb + (uint32_t)s + 2u);
      if (d == 9) {
        uint2 pp = {(uint32_t)pv[0] | ((uint32_t)pv[1] << 16),
                    (uint32_t)pv[2] | ((uint32_t)pv[3] << 16)};
        *reinterpret_cast<uint2*>(Ypack + (size_t)(tl * 16 + g) * 4096 + (half * 512 + tid) * 4) = pp;
      }
    }
#pragma unroll
    for (int r = 0; r < 4; ++r) {
      int m2 = m2b + r;
      ystate[(size_t)(g * 16 + m2) * 256 + col] = yc[r];
      ypstate[(size_t)(g * 16 + m2) * 256 + col] = ylast[r];
    }
  }
}

// out[t] = Y[t] @ W_c^T + b_c.  Ypack is C/D-order; transpose via LDS here.
__global__ __launch_bounds__(512) void k_out(const u16* __restrict__ Ypack, const u16* __restrict__ Wcpack,
                                             const float* __restrict__ b_c, float* __restrict__ out, int t0) {
  __shared__ u16 yl[4 * 4096];
  int tl = blockIdx.x; int mh = blockIdx.y;
  int tid = threadIdx.x; int l = tid & 63; int wv = tid >> 6;
  for (int i = tid; i < 4096; i += 512) {
    int pg = i >> 10; int j = i & 1023;
    uint2 v = *reinterpret_cast<const uint2*>(
        Ypack + ((size_t)(tl * 16 + mh * 4 + pg)) * 4096 + (size_t)j * 4);
    int wvp = (j >> 6) & 7, lp = j & 63, hf = j >> 9;
    int colp = hf * 128 + wvp * 16 + (lp & 15);
    int mb = 4 * (lp >> 4);
    int base = pg * 4096 + fslot(colp, mb);
    yl[base] = (u16)(v.x & 0xffffu);
    yl[base + 8] = (u16)(v.x >> 16);
    yl[base + 16] = (u16)(v.y & 0xffffu);
    yl[base + 24] = (u16)(v.y >> 16);
  }
  __syncthreads();
  int gl = wv >> 1; int nh = wv & 1;
  int mt = mh * 4 + gl;
  bf16x8_t af[8];
#pragma unroll
  for (int kk = 0; kk < 8; ++kk)
    af[kk] = *reinterpret_cast<const bf16x8_t*>(yl + gl * 4096 + kk * 512 + l * 8);
#pragma unroll 1
  for (int ntl = 0; ntl < 8; ++ntl) {
    int nt = nh * 8 + ntl;
    f32x4_t acc = {0.f, 0.f, 0.f, 0.f};
    const u16* bp = Wcpack + ((size_t)nt * 8 * 64 + l) * 8;
#pragma unroll
    for (int kk = 0; kk < 8; ++kk) {
      bf16x8_t bfr = *reinterpret_cast<const bf16x8_t*>(bp + kk * 512);
      acc = mfma16(af[kk], bfr, acc);
    }
    int n = (nt << 4) | (l & 15);
    float bc = b_c[n];
#pragma unroll
    for (int r = 0; r < 4; ++r) {
      int m = (mt << 4) + ((l >> 4) << 2) + r;
      out[((size_t)(t0 + tl) * 256 + m) * 256 + n] = acc[r] + bc;
    }
  }
}

// ---------------------------------------------------------------------------
extern "C" void kernel_launch(void* const* d_in, const int* in_sizes, int n_in,
                              void* d_out, int out_size, void* d_ws, size_t ws_size,
                              hipStream_t stream) {
  const float* input = (const float*)d_in[0];
  const float* dt    = (const float*)d_in[1];
  const float* W_i   = (const float*)d_in[2];
  const float* b_i   = (const float*)d_in[3];
  const float* W_h   = (const float*)d_in[4];
  const float* b_h   = (const float*)d_in[5];
  const float* W_z   = (const float*)d_in[6];
  const float* b_z   = (const float*)d_in[7];
  const float* W_dt  = (const float*)d_in[8];
  const float* b_dt  = (const float*)d_in[9];
  const float* W_c   = (const float*)d_in[10];
  const float* b_c   = (const float*)d_in[11];
  const float* W_s   = (const float*)d_in[12];
  const float* b_s   = (const float*)d_in[13];
  float* out = (float*)d_out;

  char* ws = (char*)d_ws;
  size_t off = 0;
  auto alloc = [&](size_t bytes) -> char* {
    char* p = ws + off; off = (off + bytes + 255) & ~(size_t)255; return p;
  };
  u16* Epack   = (u16*)alloc((size_t)112 * 4096 * 2);
  u16* Wipack  = (u16*)alloc((size_t)64 * 4096 * 2);
  u16* Wzpack  = (u16*)alloc((size_t)16 * 4096 * 2);
  u16* Wcpack  = (u16*)alloc((size_t)16 * 4096 * 2);
  u16* Wspack  = (u16*)alloc((size_t)32 * 16 * 512 * 2);
  u16* E2pack  = (u16*)alloc((size_t)64 * 4096 * 2);
  float* bip   = (float*)alloc(1024 * 4);
  float* biasD0= (float*)alloc(1024 * 4);
  float* biasDn= (float*)alloc(1024 * 4);
  float* Wic   = (float*)alloc((size_t)1024 * 256 * 4);
  float* ystate= (float*)alloc((size_t)256 * 256 * 4);
  float* ypstate=(float*)alloc((size_t)256 * 256 * 4);
  float* zstate= (float*)alloc((size_t)256 * 256 * 4);
  uint32_t* yexch  = (uint32_t*)alloc((size_t)2 * 16 * 1024 * 16);
  uint32_t* zexch  = (uint32_t*)alloc((size_t)2 * 16 * 1024 * 16);
  size_t fixed = off;
  size_t per_slot = (size_t)131072 * 2 + 65536 * 2 + 65536 * 2 + 65536 * 2;
  size_t per_t = 10 * per_slot + (size_t)10 * 196608 * 2 + 131072 + 131072 + 524288;
  int Tc = 1;
  if (ws_size > fixed + per_t + per_slot) {
    size_t n = (ws_size - fixed - per_slot) / per_t;
    Tc = (n > 128) ? 128 : (int)n;
  }
  if (Tc < 1) Tc = 1;
  int maxslots = Tc * 10 + 1;
  u16* Apack   = (u16*)alloc((size_t)maxslots * 131072 * 2);
  u16* Sny     = (u16*)alloc((size_t)maxslots * 65536 * 2);
  u16* Snz     = (u16*)alloc((size_t)maxslots * 65536 * 2);
  u16* nyA     = (u16*)alloc((size_t)maxslots * 65536 * 2);
  u16* HNpack  = (u16*)alloc((size_t)(Tc * 10) * 196608 * 2);
  u16* inpPack = (u16*)alloc((size_t)Tc * 16 * 8 * 512 * 2);
  u16* XIpack  = (u16*)alloc((size_t)Tc * 524288);
  u16* Ypack   = (u16*)alloc((size_t)Tc * 16 * 8 * 512 * 2);

  (void)hipFuncSetAttribute((const void*)k_recur, hipFuncAttributeMaxDynamicSharedMemorySize,
                            R_LDS_BYTES);

  k_prep<<<1024, 256, 0, stream>>>(W_i, W_c, b_i, b_c, Wic, bip);
  k_bias<<<4, 256, 0, stream>>>(b_i, bip, b_h, biasD0, biasDn);
  k_packw<<<(112 * 8 * 64) / 256, 256, 0, stream>>>(Wic, 1024, W_h, Epack, 1792, 256);
  k_packw<<<(64 * 8 * 64) / 256, 256, 0, stream>>>(W_i, 1024, (const float*)nullptr, Wipack, 1024, 256);
  k_packw<<<(16 * 8 * 64) / 256, 256, 0, stream>>>(W_z, 256, (const float*)nullptr, Wzpack, 256, 256);
  k_packw<<<(16 * 8 * 64) / 256, 256, 0, stream>>>(W_c, 256, (const float*)nullptr, Wcpack, 256, 256);
  k_packw<<<(32 * 16 * 64) / 256, 256, 0, stream>>>(W_s, 512, (const float*)nullptr, Wspack, 512, 512);
  k_packe2<<<128, 256, 0, stream>>>(Wic, W_h, E2pack);

  for (int t0 = 0; t0 < 128; t0 += Tc) {
    int Tcc = (128 - t0 < Tc) ? (128 - t0) : Tc;
    int nsteps = Tcc * 10;
    int slots = nsteps + 1;
    k_gen<<<slots * 128, 1024, 0, stream>>>(Apack, t0 * 10 - 1);
    dim3 g2(slots, 4);
    k_sgemm<<<g2, 512, 0, stream>>>(Apack, Wspack, b_s, Sny, Snz, nyA);
    dim3 g3(nsteps, 6);
    k_hn<<<g3, 512, 0, stream>>>(nyA, Epack, HNpack, t0);
    int totalA = Tcc * 16 * 8 * 64;
    k_packa<<<(totalA + 255) / 256, 256, 0, stream>>>(input, t0, Tcc, inpPack);
    dim3 gx(Tcc, 8);
    k_xi<<<gx, 512, 0, stream>>>(inpPack, Wipack, XIpack);
    k_recur<<<64, 512, R_LDS_BYTES, stream>>>(dt, Epack, Wzpack, E2pack, HNpack, XIpack,
                                              biasD0, biasDn, b_z, W_dt, b_dt, Sny, Snz,
                                              Ypack, ystate, ypstate, zstate,
                                              yexch, zexch, t0, Tcc);
    dim3 ge(Tcc, 4);
    k_out<<<ge, 512, 0, stream>>>(Ypack, Wcpack, b_c, out, t0);
  }
}

// Round 16
// 6046.976 us; speedup vs baseline: 1.4647x; 1.2124x over previous
//
#include <hip/hip_runtime.h>
#include <stdint.h>

// ---------------------------------------------------------------------------
// LEM-style noisy RNN. T=128 x DIV=10 sequential steps, B=256, H=256.
// Round 16: mega-fusion. One 256-WG kernel per chunk: WGs 0-63 = recurrence
// (r13-best dual-path transport + scatterPair), WGs 64-255 = helpers that
// build chunk c+1's noise pipeline (gen+sgemm+hn per slot; packa+xi per tl)
// while the recurrence runs. Chunk buffers parity-double-buffered; dispatch
// boundary provides cross-XCD visibility (as the separate kernels relied on).
// Keeps: E2=Wic+Wh in LDS, Wz in regs, HN/XI precompute, in-register fusion.
// ---------------------------------------------------------------------------

typedef __attribute__((ext_vector_type(8))) short bf16x8_t;
typedef __attribute__((ext_vector_type(4))) float f32x4_t;
typedef __attribute__((ext_vector_type(4))) unsigned int u32x4_t;
typedef unsigned short u16;

#define R_LDS_BYTES 147712
#define H_SLOT 160
#define H_TL 32

__device__ __forceinline__ float bf2f(u16 b) {
  union { uint32_t u; float f; } v; v.u = ((uint32_t)b) << 16; return v.f;
}
__device__ __forceinline__ u16 f2bf(float f) {
  union { float f; uint32_t u; } v; v.f = f;
  uint32_t x = v.u;
  return (u16)((x + 0x7FFFu + ((x >> 16) & 1u)) >> 16);   // RNE
}
__device__ __forceinline__ f32x4_t mfma16(bf16x8_t a, bf16x8_t b, f32x4_t c) {
  return __builtin_amdgcn_mfma_f32_16x16x32_bf16(a, b, c, 0, 0, 0);
}
__device__ __forceinline__ float sigm(float x) { return 1.0f / (1.0f + __expf(-x)); }
__device__ __forceinline__ float tanh_f(float x) {
  float t = __expf(-2.0f * fabsf(x));
  float r = (1.0f - t) / (1.0f + t);
  return x < 0.0f ? -r : r;
}

// A-frag slot for (k in [0,256), row m in [0,16))
__device__ __forceinline__ int fslot(int k, int m) {
  return ((k >> 5) * 512) + (((((k & 15) >> 2) << 4) | m) << 3) +
         ((k & 3) | (((k >> 4) & 1) << 2));
}
__device__ __forceinline__ int fragK(int l, int e) {
  return ((l >> 4) << 2) + (e & 3) + ((e >> 2) << 4);
}

// ---- dual-path transport (r13 measured-best) ----
__device__ __forceinline__ void publish(uint32_t* p3, uint32_t* p2,
                                        uint32_t w0, uint32_t w1, uint32_t seq) {
  u32x4_t pay; pay.x = w0; pay.y = seq; pay.z = w1; pay.w = seq;
  asm volatile("global_store_dwordx4 %0, %2, off sc0 sc1\n\t"
               "global_store_dwordx4 %1, %2, off sc0"
               :: "v"(p3), "v"(p2), "v"(pay) : "memory");
}
__device__ __forceinline__ void pollpair_dual(const uint32_t* p2, const uint32_t* p3,
                                              uint32_t seq, u32x4_t* a, u32x4_t* b) {
  while (true) {
    u32x4_t x, y;
    asm volatile("global_load_dwordx4 %0, %2, off sc0\n\t"
                 "global_load_dwordx4 %1, %3, off sc0\n\t"
                 "s_waitcnt vmcnt(0)"
                 : "=&v"(x), "=&v"(y) : "v"(p2), "v"(p2 + 4) : "memory");
    if (x.y == seq && x.w == seq && y.y == seq && y.w == seq) { *a = x; *b = y; return; }
    asm volatile("global_load_dwordx4 %0, %2, off sc0 sc1\n\t"
                 "global_load_dwordx4 %1, %3, off sc0 sc1\n\t"
                 "s_waitcnt vmcnt(0)"
                 : "=&v"(x), "=&v"(y) : "v"(p3), "v"(p3 + 4) : "memory");
    if (x.y == seq && x.w == seq && y.y == seq && y.w == seq) { *a = x; *b = y; return; }
    __builtin_amdgcn_s_sleep(1);
  }
}
// scatter a PAIR of C/D-order payload slots (j even: j, j+1) as 4 u32 writes.
__device__ __forceinline__ void scatterPair(u16* dst, int j, u32x4_t pa, u32x4_t pb) {
  int wvp = (j >> 6) & 7, lp = j & 63, hf = j >> 9;
  int colp = hf * 128 + wvp * 16 + (lp & 15);   // even
  int mb = 4 * (lp >> 4);
  int base = fslot(colp, mb);                   // even
  uint32_t* d = (uint32_t*)(dst + base);
  d[0]  = (pa.x & 0xffffu) | ((pb.x & 0xffffu) << 16);
  d[4]  = (pa.x >> 16)     | (pb.x & 0xffff0000u);
  d[8]  = (pa.z & 0xffffu) | ((pb.z & 0xffffu) << 16);
  d[12] = (pa.z >> 16)     | (pb.z & 0xffff0000u);
}

// ---- JAX threefry2x32 (20 rounds) ----
__device__ __forceinline__ void threefry(uint32_t k0, uint32_t k1, uint32_t x0, uint32_t x1,
                                         uint32_t* o0, uint32_t* o1) {
  uint32_t ks2 = k0 ^ k1 ^ 0x1BD11BDAu;
  x0 += k0; x1 += k1;
#define TFR(rot) { x0 += x1; x1 = (x1 << rot) | (x1 >> (32 - rot)); x1 ^= x0; }
  TFR(13) TFR(15) TFR(26) TFR(6)   x0 += k1;  x1 += ks2 + 1u;
  TFR(17) TFR(29) TFR(16) TFR(24)  x0 += ks2; x1 += k0 + 2u;
  TFR(13) TFR(15) TFR(26) TFR(6)   x0 += k0;  x1 += k1 + 3u;
  TFR(17) TFR(29) TFR(16) TFR(24)  x0 += k1;  x1 += ks2 + 4u;
  TFR(13) TFR(15) TFR(26) TFR(6)   x0 += ks2; x1 += k0 + 5u;
#undef TFR
  *o0 = x0; *o1 = x1;
}

// bits -> N(0,1), matches jax.random.normal f32 (XLA erfinv poly)
__device__ __forceinline__ float bits2normal(uint32_t bits) {
  union { uint32_t u; float f; } cv; cv.u = 0x3F800000u | (bits >> 9);
  float f = cv.f - 1.0f;
  float u = fmaf(f, 2.0f, -0.99999994f);
  u = fmaxf(u, -0.99999994f);
  float w = -log1pf(-u * u);
  float p;
  if (w < 5.0f) {
    w = w - 2.5f;
    p = 2.81022636e-08f;
    p = fmaf(p, w, 3.43273939e-07f);
    p = fmaf(p, w, -3.5233877e-06f);
    p = fmaf(p, w, -4.39150654e-06f);
    p = fmaf(p, w, 0.00021858087f);
    p = fmaf(p, w, -0.00125372503f);
    p = fmaf(p, w, -0.00417768164f);
    p = fmaf(p, w, 0.246640727f);
    p = fmaf(p, w, 1.50140941f);
  } else {
    w = sqrtf(w) - 3.0f;
    p = -0.000200214257f;
    p = fmaf(p, w, 0.000100950558f);
    p = fmaf(p, w, 0.00134934322f);
    p = fmaf(p, w, -0.00367342844f);
    p = fmaf(p, w, 0.00573950773f);
    p = fmaf(p, w, -0.0076224613f);
    p = fmaf(p, w, 0.00943887047f);
    p = fmaf(p, w, 1.00167406f);
    p = fmaf(p, w, 2.83297682f);
  }
  return 1.41421354f * p * u;
}

// ---------------------------------------------------------------------------
__global__ void k_prep(const float* __restrict__ W_i, const float* __restrict__ W_c,
                       const float* __restrict__ b_i, const float* __restrict__ b_c,
                       float* __restrict__ Wic, float* __restrict__ bip) {
  __shared__ float wi[256];
  __shared__ float red[256];
  int o = blockIdx.x; int tid = threadIdx.x;
  wi[tid] = W_i[o * 256 + tid];
  __syncthreads();
  float acc = 0.f;
  for (int j = 0; j < 256; ++j) acc = fmaf(wi[j], W_c[j * 256 + tid], acc);
  Wic[(size_t)o * 256 + tid] = acc;
  red[tid] = wi[tid] * b_c[tid];
  __syncthreads();
  for (int s = 128; s > 0; s >>= 1) { if (tid < s) red[tid] += red[tid + s]; __syncthreads(); }
  if (tid == 0) bip[o] = b_i[o] + red[0];
}

__global__ void k_bias(const float* __restrict__ b_i, const float* __restrict__ bip,
                       const float* __restrict__ b_h,
                       float* __restrict__ biasD0, float* __restrict__ biasDn) {
  int c = blockIdx.x * 256 + threadIdx.x;
  float bh = (c < 512) ? b_h[c] : (c >= 768 ? b_h[c - 256] : 0.f);
  biasD0[c] = b_i[c] + bh;
  biasDn[c] = bip[c] + bh;
}

__global__ void k_packw(const float* __restrict__ srcA, int rowsA, const float* __restrict__ srcB,
                        u16* __restrict__ dst, int O, int K) {
  int t = blockIdx.x * blockDim.x + threadIdx.x;
  int KK = K >> 5;
  int total = (O >> 4) * KK * 64;
  if (t >= total) return;
  int l = t & 63; int kk = (t >> 6) % KK; int to = t / (64 * KK);
  int n = (to << 4) | (l & 15);
  int kb = (kk << 5) + ((l >> 4) << 2);
  const float* src = (n < rowsA) ? (srcA + (size_t)n * K) : (srcB + (size_t)(n - rowsA) * K);
  u16 out[8];
#pragma unroll
  for (int e = 0; e < 8; ++e) out[e] = f2bf(src[kb + (e & 3) + ((e >> 2) << 4)]);
  *reinterpret_cast<uint4*>(dst + (size_t)t * 8) = *reinterpret_cast<const uint4*>(out);
}

// E2 = Wic + Wh aligned
__global__ void k_packe2(const float* __restrict__ Wic, const float* __restrict__ Wh,
                         u16* __restrict__ dst) {
  int t = blockIdx.x * blockDim.x + threadIdx.x;
  int l = t & 63; int kk = (t >> 6) & 7; int to = t >> 9;
  int n = (to << 4) | (l & 15);
  int kb = (kk << 5) + ((l >> 4) << 2);
  u16 out[8];
#pragma unroll
  for (int e = 0; e < 8; ++e) {
    int k = kb + (e & 3) + ((e >> 2) << 4);
    float v = Wic[(size_t)n * 256 + k];
    if (n < 512) v += Wh[(size_t)n * 256 + k];
    else if (n >= 768) v += Wh[(size_t)(n - 256) * 256 + k];
    out[e] = f2bf(v);
  }
  *reinterpret_cast<uint4*>(dst + (size_t)t * 8) = *reinterpret_cast<const uint4*>(out);
}

__global__ void k_packa(const float* __restrict__ inp, int t0, int Tcc, u16* __restrict__ dst) {
  int t = blockIdx.x * blockDim.x + threadIdx.x;
  int total = Tcc * 16 * 8 * 64;
  if (t >= total) return;
  int l = t & 63; int kk = (t >> 6) & 7; int mt = (t >> 9) & 15; int tl = t >> 13;
  int b = (mt << 4) | (l & 15);
  int kb = (kk << 5) + ((l >> 4) << 2);
  const float* src = inp + ((size_t)(t0 + tl) * 256 + b) * 256;
  u16 out[8];
#pragma unroll
  for (int e = 0; e < 8; ++e) out[e] = f2bf(src[kb + (e & 3) + ((e >> 2) << 4)]);
  *reinterpret_cast<uint4*>(dst + (size_t)t * 8) = *reinterpret_cast<const uint4*>(out);
}

// noise gen; slot sl = global noise step gstep0+sl
__global__ void k_gen(u16* __restrict__ Apack, int gstep0) {
  int sl = blockIdx.x >> 7;
  int tb = (blockIdx.x & 127) * 1024 + threadIdx.x;
  __shared__ uint32_t kf[2];
  if (threadIdx.x == 0) {
    uint32_t o0, o1;
    threefry(0u, 1234u, 0u, (uint32_t)(gstep0 + sl), &o0, &o1);
    kf[0] = o0; kf[1] = o1;
  }
  __syncthreads();
  int e = tb & 7; int l = (tb >> 3) & 63; int kk = (tb >> 9) & 15; int mt = tb >> 13;
  int b = (mt << 4) | (l & 15);
  int c = (kk << 5) + fragK(l, e);
  uint32_t i = (uint32_t)(b * 512 + c);
  uint32_t o0, o1;
  threefry(kf[0], kf[1], 0u, i, &o0, &o1);
  Apack[(size_t)sl * 131072 + tb] = f2bf(bits2normal(o0 ^ o1));
}

// S = tanh(noise @ Ws^T + b_s) -> Sny/Snz + nyA
__global__ __launch_bounds__(512) void k_sgemm(const u16* __restrict__ Apack,
                                               const u16* __restrict__ Wspack,
                                               const float* __restrict__ b_s,
                                               u16* __restrict__ Sny, u16* __restrict__ Snz,
                                               u16* __restrict__ nyA) {
  int sl = blockIdx.x; int nq = blockIdx.y;
  int l = threadIdx.x & 63; int wv = threadIdx.x >> 6;
  const u16* Ab = Apack + (size_t)sl * 131072;
#pragma unroll 1
  for (int mtl = 0; mtl < 2; ++mtl) {
    int mt = 2 * wv + mtl;
    bf16x8_t af[16];
#pragma unroll
    for (int kk = 0; kk < 16; ++kk)
      af[kk] = *reinterpret_cast<const bf16x8_t*>(Ab + ((size_t)(mt * 16 + kk) * 64 + l) * 8);
#pragma unroll 1
    for (int ntl = 0; ntl < 8; ++ntl) {
      int nt = nq * 8 + ntl;
      f32x4_t acc = {0.f, 0.f, 0.f, 0.f};
#pragma unroll
      for (int kk = 0; kk < 16; ++kk) {
        bf16x8_t bfr = *reinterpret_cast<const bf16x8_t*>(Wspack + ((size_t)(nt * 16 + kk) * 64 + l) * 8);
        acc = mfma16(af[kk], bfr, acc);
      }
      int n = (nt << 4) | (l & 15);
      float bs = b_s[n];
#pragma unroll
      for (int r = 0; r < 4; ++r) {
        int m = (mt << 4) + ((l >> 4) << 2) + r;
        u16 v = f2bf(tanh_f(acc[r] + bs));
        int g = m >> 4, row = m & 15;
        if (n >= 256) {
          int h = n - 256; int hz = h >> 7;
          int tidc = ((h >> 4) & 7) * 64 + ((row >> 2) << 4) + (h & 15);
          Snz[((((size_t)sl * 16 + g) * 2 + hz) * 512 + tidc) * 4 + (row & 3)] = v;
        } else {
          int hy = n >> 7;
          int tidc = ((n >> 4) & 7) * 64 + ((row >> 2) << 4) + (n & 15);
          Sny[((((size_t)sl * 16 + g) * 2 + hy) * 512 + tidc) * 4 + (row & 3)] = v;
          int kk2 = n >> 5;
          int la = (((n & 15) >> 2) << 4) | row;
          int ea = (n & 3) | (((n >> 4) & 1) << 2);
          nyA[(((size_t)sl * 16 + g) * 8 + kk2) * 512 + la * 8 + ea] = v;
        }
      }
    }
  }
}

// HN[j] = Wh @ ny(slot j), C/D layout
__global__ __launch_bounds__(512) void k_hn(const u16* __restrict__ nyA,
                                            const u16* __restrict__ Epack,
                                            u16* __restrict__ HNpack, int t0) {
  int j = blockIdx.x; int nq = blockIdx.y;
  int l = threadIdx.x & 63; int wv = threadIdx.x >> 6;
  int nt = nq * 8 + wv;
  if (j == 0 && t0 == 0) {
    uint2 z = {0u, 0u};
#pragma unroll 1
    for (int mt = 0; mt < 16; ++mt)
      *reinterpret_cast<uint2*>(&HNpack[(((size_t)j * 16 + mt) * 48 + nt) * 256 + l * 4]) = z;
    return;
  }
  bf16x8_t bf[8];
  const u16* bp = Epack + (size_t)(64 + nt) * 4096 + (size_t)l * 8;
#pragma unroll
  for (int kk = 0; kk < 8; ++kk)
    bf[kk] = *reinterpret_cast<const bf16x8_t*>(bp + kk * 512);
#pragma unroll 1
  for (int mt = 0; mt < 16; ++mt) {
    const u16* ap = nyA + (((size_t)j * 16 + mt) * 8) * 512 + (size_t)l * 8;
    f32x4_t acc = {0.f, 0.f, 0.f, 0.f};
#pragma unroll
    for (int kk = 0; kk < 8; ++kk)
      acc = mfma16(*reinterpret_cast<const bf16x8_t*>(ap + kk * 512), bf[kk], acc);
    union { u16 h[4]; uint2 v; } o;
#pragma unroll
    for (int r = 0; r < 4; ++r) o.h[r] = f2bf(acc[r]);
    *reinterpret_cast<uint2*>(&HNpack[(((size_t)j * 16 + mt) * 48 + nt) * 256 + l * 4]) = o.v;
  }
}

// XI[tl][g] = x @ Wi^T, C/D layout
__global__ __launch_bounds__(512) void k_xi(const u16* __restrict__ inpPack,
                                            const u16* __restrict__ Wipack,
                                            u16* __restrict__ XIpack) {
  int tl = blockIdx.x; int nb = blockIdx.y;
  int l = threadIdx.x & 63; int wv = threadIdx.x >> 6;
  int nt = nb * 8 + wv;
  bf16x8_t bf[8];
  const u16* bp = Wipack + (size_t)nt * 4096 + (size_t)l * 8;
#pragma unroll
  for (int kk = 0; kk < 8; ++kk)
    bf[kk] = *reinterpret_cast<const bf16x8_t*>(bp + kk * 512);
#pragma unroll 1
  for (int g = 0; g < 16; ++g) {
    const u16* ap = inpPack + (size_t)(tl * 16 + g) * 4096 + (size_t)l * 8;
    f32x4_t acc = {0.f, 0.f, 0.f, 0.f};
#pragma unroll
    for (int kk = 0; kk < 8; ++kk)
      acc = mfma16(*reinterpret_cast<const bf16x8_t*>(ap + kk * 512), bf[kk], acc);
    union { u16 h[4]; uint2 v; } o;
#pragma unroll
    for (int r = 0; r < 4; ++r) o.h[r] = f2bf(acc[r]);
    *reinterpret_cast<uint2*>(&XIpack[(((size_t)tl * 16 + g) * 64 + nt) * 256 + l * 4]) = o.v;
  }
}

// ---------------------------------------------------------------------------
// Mega kernel: 256 WGs x 512. WGs 0-63: recurrence chunk c (parity pc).
// WGs 64-255: helpers building chunk c+1 (parity pn). No __restrict__ (alias).
__global__ __launch_bounds__(512, 2) void k_mega(
    const float* dt, const u16* Epack, const u16* Wzpack, const u16* E2pack,
    u16* HNpack, u16* XIpack,
    const float* biasD0, const float* biasDn, const float* b_z,
    const float* W_dt, const float* b_dt,
    u16* Sny, u16* Snz,
    u16* Ypack, float* ystate, float* ypstate, float* zstate,
    uint32_t* yexch, uint32_t* yexch2, uint32_t* zexch, uint32_t* zexch2,
    const float* input, const u16* Wipack, const u16* Wspack, const float* b_s,
    u16* Apack, u16* nyA, u16* inpPack,
    int t0, int Tcc, int pc, int t0b, int Tcc2, int pn,
    unsigned long snyS, unsigned long hnS, unsigned long xiS, unsigned long inpS)
{
  extern __shared__ char lds_raw[];
  const int tid = threadIdx.x;
  const int l = tid & 63;
  const int wv = tid >> 6;

  if (blockIdx.x >= 64) {
    // =================== HELPERS: build chunk c+1 ===================
    if (Tcc2 <= 0) return;
    int hw = blockIdx.x - 64;
    u16* SnyN = Sny + (size_t)pn * snyS;
    u16* SnzN = Snz + (size_t)pn * snyS;
    u16* HNN  = HNpack + (size_t)pn * hnS;
    u16* XIN  = XIpack + (size_t)pn * xiS;
    u16* inpN = inpPack + (size_t)pn * inpS;
    int slots2 = Tcc2 * 10 + 1;
    int nst2 = Tcc2 * 10;
    int gstep0 = t0b * 10 - 1;
    if (hw < H_SLOT) {
      for (int sl = hw; sl < slots2; sl += H_SLOT) {
        // ---- gen slot sl ----
        uint32_t fk0, fk1;
        threefry(0u, 1234u, 0u, (uint32_t)(gstep0 + sl), &fk0, &fk1);
        for (int i = tid; i < 131072; i += 512) {
          int e = i & 7; int l2 = (i >> 3) & 63; int kq = (i >> 9) & 15; int mt = i >> 13;
          int b = (mt << 4) | (l2 & 15);
          int cc = (kq << 5) + fragK(l2, e);
          uint32_t o0, o1;
          threefry(fk0, fk1, 0u, (uint32_t)(b * 512 + cc), &o0, &o1);
          Apack[(size_t)sl * 131072 + i] = f2bf(bits2normal(o0 ^ o1));
        }
        __syncthreads();
        // ---- sgemm slot sl (all 4 nq) ----
        const u16* Ab = Apack + (size_t)sl * 131072;
#pragma unroll 1
        for (int nq = 0; nq < 4; ++nq) {
#pragma unroll 1
          for (int mtl = 0; mtl < 2; ++mtl) {
            int mt = 2 * wv + mtl;
            bf16x8_t af[16];
#pragma unroll
            for (int kk = 0; kk < 16; ++kk)
              af[kk] = *reinterpret_cast<const bf16x8_t*>(Ab + ((size_t)(mt * 16 + kk) * 64 + l) * 8);
#pragma unroll 1
            for (int ntl = 0; ntl < 8; ++ntl) {
              int nt = nq * 8 + ntl;
              f32x4_t acc = {0.f, 0.f, 0.f, 0.f};
#pragma unroll
              for (int kk = 0; kk < 16; ++kk) {
                bf16x8_t bfr = *reinterpret_cast<const bf16x8_t*>(
                    Wspack + ((size_t)(nt * 16 + kk) * 64 + l) * 8);
                acc = mfma16(af[kk], bfr, acc);
              }
              int n = (nt << 4) | (l & 15);
              float bs = b_s[n];
#pragma unroll
              for (int r = 0; r < 4; ++r) {
                int m = (mt << 4) + ((l >> 4) << 2) + r;
                u16 v = f2bf(tanh_f(acc[r] + bs));
                int g = m >> 4, row = m & 15;
                if (n >= 256) {
                  int h = n - 256; int hz = h >> 7;
                  int tidc = ((h >> 4) & 7) * 64 + ((row >> 2) << 4) + (h & 15);
                  SnzN[((((size_t)sl * 16 + g) * 2 + hz) * 512 + tidc) * 4 + (row & 3)] = v;
                } else {
                  int hy = n >> 7;
                  int tidc = ((n >> 4) & 7) * 64 + ((row >> 2) << 4) + (n & 15);
                  SnyN[((((size_t)sl * 16 + g) * 2 + hy) * 512 + tidc) * 4 + (row & 3)] = v;
                  int kk2 = n >> 5;
                  int la = (((n & 15) >> 2) << 4) | row;
                  int ea = (n & 3) | (((n >> 4) & 1) << 2);
                  nyA[(((size_t)sl * 16 + g) * 8 + kk2) * 512 + la * 8 + ea] = v;
                }
              }
            }
          }
        }
        __syncthreads();
        // ---- hn slot sl (t0b > 0 always here) ----
        if (sl < nst2) {
#pragma unroll 1
          for (int q = 0; q < 6; ++q) {
            int nt = q * 8 + wv;
            bf16x8_t bfw[8];
            const u16* bp = Epack + (size_t)(64 + nt) * 4096 + (size_t)l * 8;
#pragma unroll
            for (int kk = 0; kk < 8; ++kk)
              bfw[kk] = *reinterpret_cast<const bf16x8_t*>(bp + kk * 512);
#pragma unroll 1
            for (int mt = 0; mt < 16; ++mt) {
              const u16* ap = nyA + (((size_t)sl * 16 + mt) * 8) * 512 + (size_t)l * 8;
              f32x4_t acc = {0.f, 0.f, 0.f, 0.f};
#pragma unroll
              for (int kk = 0; kk < 8; ++kk)
                acc = mfma16(*reinterpret_cast<const bf16x8_t*>(ap + kk * 512), bfw[kk], acc);
              union { u16 h[4]; uint2 v; } o;
#pragma unroll
              for (int r = 0; r < 4; ++r) o.h[r] = f2bf(acc[r]);
              *reinterpret_cast<uint2*>(&HNN[(((size_t)sl * 16 + mt) * 48 + nt) * 256 + l * 4]) = o.v;
            }
          }
        }
        __syncthreads();
      }
    } else {
      int hx = hw - H_SLOT;   // [0, H_TL)
      for (int tl = hx; tl < Tcc2; tl += H_TL) {
        // ---- packa tl ----
        for (int i = tid; i < 8192; i += 512) {
          int t = tl * 8192 + i;
          int l2 = t & 63; int kk = (t >> 6) & 7; int mt = (t >> 9) & 15;
          int b = (mt << 4) | (l2 & 15);
          int kb = (kk << 5) + ((l2 >> 4) << 2);
          const float* src = input + ((size_t)(t0b + tl) * 256 + b) * 256;
          u16 o[8];
#pragma unroll
          for (int e = 0; e < 8; ++e) o[e] = f2bf(src[kb + (e & 3) + ((e >> 2) << 4)]);
          *reinterpret_cast<uint4*>(inpN + (size_t)t * 8) = *reinterpret_cast<const uint4*>(o);
        }
        __syncthreads();
        // ---- xi tl ----
#pragma unroll 1
        for (int nb = 0; nb < 8; ++nb) {
          int nt = nb * 8 + wv;
          bf16x8_t bfw[8];
          const u16* bp = Wipack + (size_t)nt * 4096 + (size_t)l * 8;
#pragma unroll
          for (int kk = 0; kk < 8; ++kk)
            bfw[kk] = *reinterpret_cast<const bf16x8_t*>(bp + kk * 512);
#pragma unroll 1
          for (int g = 0; g < 16; ++g) {
            const u16* ap = inpN + (size_t)(tl * 16 + g) * 4096 + (size_t)l * 8;
            f32x4_t acc = {0.f, 0.f, 0.f, 0.f};
#pragma unroll
            for (int kk = 0; kk < 8; ++kk)
              acc = mfma16(*reinterpret_cast<const bf16x8_t*>(ap + kk * 512), bfw[kk], acc);
            union { u16 h[4]; uint2 v; } o;
#pragma unroll
            for (int r = 0; r < 4; ++r) o.h[r] = f2bf(acc[r]);
            *reinterpret_cast<uint2*>(&XIN[(((size_t)tl * 16 + g) * 64 + nt) * 256 + l * 4]) = o.v;
          }
        }
        __syncthreads();
      }
    }
    return;
  }

  // =================== RECURRENCE (chunk c, parity pc) ===================
  u16* wlds = (u16*)lds_raw;            // 65536 u16 (128KB): E2 tiles
  u16* buf  = wlds + 65536;             // 8192 u16
  float* sc  = (float*)(buf + 8192);    // 48
  float* scP = sc + 48;                 // 16

  const u16* SnyP = Sny + (size_t)pc * snyS;
  const u16* SnzP = Snz + (size_t)pc * snyS;
  const u16* HNp  = HNpack + (size_t)pc * hnS;
  const u16* XIp  = XIpack + (size_t)pc * xiS;

  const int wgid = blockIdx.x;
  const int g = wgid & 15;
  const int role = wgid >> 4;
  const bool isY = role < 2;
  const int half = role & 1;
  const int nsteps = Tcc * 10;
  const int m2b = 4 * (l >> 4);
  const int col = half * 128 + wv * 16 + (l & 15);
  const uint32_t gb = (uint32_t)(t0 * 10);

  int wiT0, whT0, hnT0, wiT1, whT1 = -1, hnT1 = -1;
  if (isY) {
    wiT0 = half * 8 + wv;       whT0 = 64 + wiT0;  hnT0 = wiT0;
    wiT1 = 32 + half * 8 + wv;
  } else {
    wiT0 = 16 + half * 8 + wv;  whT0 = 64 + wiT0;  hnT0 = wiT0;
    wiT1 = 48 + half * 8 + wv;  whT1 = 96 + half * 8 + wv;  hnT1 = 32 + half * 8 + wv;
  }
  float b0d0 = biasD0[wiT0 * 16 + (l & 15)], b0dn = biasDn[wiT0 * 16 + (l & 15)];
  float b1d0 = biasD0[wiT1 * 16 + (l & 15)], b1dn = biasDn[wiT1 * 16 + (l & 15)];

  // preload E2 tiles into LDS
  for (int i = tid; i < 8192; i += 512) {
    int t = i >> 9; int o = (i & 511) << 3;
    int gt;
    if (isY) gt = (t < 8) ? (half * 8 + t) : (32 + half * 8 + (t - 8));
    else     gt = (t < 8) ? (16 + half * 8 + t) : (48 + half * 8 + (t - 8));
    *reinterpret_cast<uint4*>(wlds + t * 4096 + o) =
        *reinterpret_cast<const uint4*>(E2pack + (size_t)gt * 4096 + o);
  }

  float zc[4], yc[4], ylast[4];
  bf16x8_t wzf[8];
  float bzr = 0.f;
  float wdt0 = W_dt[0], wdt1 = W_dt[1], bdt0 = b_dt[0], bdt1 = b_dt[1];

  if (isY) {
    bzr = b_z[col];
#pragma unroll
    for (int kk = 0; kk < 8; ++kk)
      wzf[kk] = *reinterpret_cast<const bf16x8_t*>(
          Wzpack + (size_t)(half * 8 + wv) * 4096 + (size_t)kk * 512 + (size_t)l * 8);
    u16 v[4];
#pragma unroll
    for (int r = 0; r < 4; ++r) {
      int m2 = m2b + r;
      yc[r] = (t0 == 0) ? 0.f : ystate[(size_t)(g * 16 + m2) * 256 + col];
      ylast[r] = 0.f;
      float vv = (t0 == 0) ? 0.f : ypstate[(size_t)(g * 16 + m2) * 256 + col];
      v[r] = f2bf(vv);
    }
    int base = fslot(col, m2b);
    buf[base] = v[0]; buf[base + 8] = v[1]; buf[base + 16] = v[2]; buf[base + 24] = v[3];
    uint32_t w0 = (uint32_t)v[0] | ((uint32_t)v[1] << 16);
    uint32_t w1 = (uint32_t)v[2] | ((uint32_t)v[3] << 16);
    size_t so = ((size_t)g * 1024 + half * 512 + tid) * 4;
    publish(yexch + so, yexch2 + so, w0, w1, gb + 1u);
  } else {
#pragma unroll
    for (int r = 0; r < 4; ++r)
      zc[r] = (t0 == 0) ? 0.f : zstate[(size_t)(g * 16 + m2b + r) * 256 + col];
  }

  if (!isY) {
    // ---- Z loop ----
    for (int s = 0; s < nsteps; ++s) {
      int d = s % 10;
      uint2 nsv = *reinterpret_cast<const uint2*>(
          SnzP + ((((size_t)(s + 1) * 16 + g) * 2 + half) * 512 + tid) * 4);
      size_t HNs = ((size_t)s * 16 + g) * 48;
      uint2 hv0 = *reinterpret_cast<const uint2*>(HNp + (HNs + hnT0) * 256 + l * 4);
      uint2 hv1 = *reinterpret_cast<const uint2*>(HNp + (HNs + hnT1) * 256 + l * 4);
      uint2 xi0 = {0u, 0u}, xi1 = {0u, 0u};
      if (d == 0) {
        int tl = s / 10;
        size_t XIs = ((size_t)tl * 16 + g) * 64;
        xi0 = *reinterpret_cast<const uint2*>(XIp + (XIs + wiT0) * 256 + l * 4);
        xi1 = *reinterpret_cast<const uint2*>(XIp + (XIs + wiT1) * 256 + l * 4);
        if (tid < 16) {
          float dl = dt[(size_t)(t0 + tl) * 256 + g * 16 + tid] * 0.1f;
          sc[tid] = dl;
          sc[16 + tid] = sigm(fmaf(dl, wdt0, bdt0));
          sc[32 + tid] = sigm(fmaf(dl, wdt1, bdt1));
          int tp = t0 + tl - 1; if (tp < 0) tp = 0;
          scP[tid] = dt[(size_t)tp * 256 + g * 16 + tid] * 0.1f;
        }
      }
      uint32_t seq = gb + (uint32_t)s + 1u;
      size_t bo = (((size_t)(s & 1) * 16 + g) * 1024 + 2 * tid) * 4;
      u32x4_t pa, pb;
      pollpair_dual(yexch2 + bo, yexch + bo, seq, &pa, &pb);
      u16* yb = buf + (s & 1) * 4096;
      scatterPair(yb, 2 * tid, pa, pb);
      __syncthreads();
      bf16x8_t ay[8];
#pragma unroll
      for (int kk = 0; kk < 8; ++kk)
        ay[kk] = *reinterpret_cast<const bf16x8_t*>(yb + kk * 512 + l * 8);
      float scv[4];
#pragma unroll
      for (int r = 0; r < 4; ++r) scv[r] = (d == 0 ? scP[m2b + r] : sc[m2b + r]);
      f32x4_t a0 = {0.f, 0.f, 0.f, 0.f}, a1 = {0.f, 0.f, 0.f, 0.f};
      if (d == 0) {
        const u16* hp0 = Epack + (size_t)whT0 * 4096 + (size_t)l * 8;
        const u16* hp1 = Epack + (size_t)whT1 * 4096 + (size_t)l * 8;
#pragma unroll
        for (int kk = 0; kk < 8; ++kk)
          a0 = mfma16(ay[kk], *reinterpret_cast<const bf16x8_t*>(hp0 + kk * 512), a0);
#pragma unroll
        for (int kk = 0; kk < 8; ++kk)
          a1 = mfma16(ay[kk], *reinterpret_cast<const bf16x8_t*>(hp1 + kk * 512), a1);
      } else {
        const u16* w0p = wlds + wv * 4096 + l * 8;
        const u16* w1p = wlds + (8 + wv) * 4096 + l * 8;
#pragma unroll
        for (int kk = 0; kk < 8; ++kk)
          a0 = mfma16(ay[kk], *reinterpret_cast<const bf16x8_t*>(w0p + kk * 512), a0);
#pragma unroll
        for (int kk = 0; kk < 8; ++kk)
          a1 = mfma16(ay[kk], *reinterpret_cast<const bf16x8_t*>(w1p + kk * 512), a1);
      }
      const u16* h0 = (const u16*)&hv0; const u16* h1 = (const u16*)&hv1;
      const u16* x0 = (const u16*)&xi0; const u16* x1 = (const u16*)&xi1;
      const u16* nzp = (const u16*)&nsv;
      u16 zv[4];
#pragma unroll
      for (int r = 0; r < 4; ++r) {
        int m2 = m2b + r;
        float r0 = a0[r] + (d == 0 ? (b0d0 + bf2f(x0[r])) : b0dn) + scv[r] * bf2f(h0[r]);
        float r1 = a1[r] + (d == 0 ? (b1d0 + bf2f(x1[r])) : b1dn) + scv[r] * bf2f(h1[r]);
        float ms = sc[32 + m2] * sigm(r0);
        float zn = (1.0f - ms) * zc[r] + ms * tanh_f(r1);
        zv[r] = f2bf(zn);
        zc[r] = fmaf(bf2f(nzp[r]), sc[m2], zn);
      }
      uint32_t w0z = (uint32_t)zv[0] | ((uint32_t)zv[1] << 16);
      uint32_t w1z = (uint32_t)zv[2] | ((uint32_t)zv[3] << 16);
      size_t so = (((size_t)(s & 1) * 16 + g) * 1024 + half * 512 + tid) * 4;
      publish(zexch + so, zexch2 + so, w0z, w1z, seq);
    }
#pragma unroll
    for (int r = 0; r < 4; ++r)
      zstate[(size_t)(g * 16 + m2b + r) * 256 + col] = zc[r];
  } else {
    // ---- Y loop ----
    for (int s = 0; s < nsteps; ++s) {
      int d = s % 10, tl = s / 10;
      uint2 nsv = *reinterpret_cast<const uint2*>(
          SnyP + ((((size_t)(s + 1) * 16 + g) * 2 + half) * 512 + tid) * 4);
      size_t HNs = ((size_t)s * 16 + g) * 48;
      uint2 hv0 = *reinterpret_cast<const uint2*>(HNp + (HNs + hnT0) * 256 + l * 4);
      uint2 xi0 = {0u, 0u}, xi1 = {0u, 0u};
      if (d == 0) {
        size_t XIs = ((size_t)tl * 16 + g) * 64;
        xi0 = *reinterpret_cast<const uint2*>(XIp + (XIs + wiT0) * 256 + l * 4);
        xi1 = *reinterpret_cast<const uint2*>(XIp + (XIs + wiT1) * 256 + l * 4);
        if (tid < 16) {
          float dl = dt[(size_t)(t0 + tl) * 256 + g * 16 + tid] * 0.1f;
          sc[tid] = dl;
          sc[16 + tid] = sigm(fmaf(dl, wdt0, bdt0));
          sc[32 + tid] = sigm(fmaf(dl, wdt1, bdt1));
          int tp = t0 + tl - 1; if (tp < 0) tp = 0;
          scP[tid] = dt[(size_t)tp * 256 + g * 16 + tid] * 0.1f;
        }
      }
      uint32_t seq = gb + (uint32_t)s + 1u;
      if (tid < 256) {
        int j = (1 ^ half) * 512 + 2 * tid;
        size_t bo = (((size_t)(s & 1) * 16 + g) * 1024 + j) * 4;
        u32x4_t pa, pb;
        pollpair_dual(yexch2 + bo, yexch + bo, seq, &pa, &pb);
        scatterPair(buf, j, pa, pb);
      }
      __syncthreads();                                  // BAR_1
      f32x4_t r0v, r1v;
      {
        bf16x8_t ay[8];
#pragma unroll
        for (int kk = 0; kk < 8; ++kk)
          ay[kk] = *reinterpret_cast<const bf16x8_t*>(buf + kk * 512 + l * 8);
        float scv[4];
#pragma unroll
        for (int r = 0; r < 4; ++r) scv[r] = (d == 0 ? scP[m2b + r] : sc[m2b + r]);
        f32x4_t a0 = {0.f, 0.f, 0.f, 0.f}, a1 = {0.f, 0.f, 0.f, 0.f};
        if (d == 0) {
          const u16* hp0 = Epack + (size_t)whT0 * 4096 + (size_t)l * 8;
#pragma unroll
          for (int kk = 0; kk < 8; ++kk)
            a0 = mfma16(ay[kk], *reinterpret_cast<const bf16x8_t*>(hp0 + kk * 512), a0);
        } else {
          const u16* w0p = wlds + wv * 4096 + l * 8;
          const u16* w1p = wlds + (8 + wv) * 4096 + l * 8;
#pragma unroll
          for (int kk = 0; kk < 8; ++kk)
            a0 = mfma16(ay[kk], *reinterpret_cast<const bf16x8_t*>(w0p + kk * 512), a0);
#pragma unroll
          for (int kk = 0; kk < 8; ++kk)
            a1 = mfma16(ay[kk], *reinterpret_cast<const bf16x8_t*>(w1p + kk * 512), a1);
        }
        const u16* h0 = (const u16*)&hv0;
        const u16* x0 = (const u16*)&xi0; const u16* x1 = (const u16*)&xi1;
#pragma unroll
        for (int r = 0; r < 4; ++r) {
          r0v[r] = a0[r] + (d == 0 ? (b0d0 + bf2f(x0[r])) : b0dn) + scv[r] * bf2f(h0[r]);
          r1v[r] = (d == 0) ? (b1d0 + bf2f(x1[r])) : (a1[r] + b1dn);
        }
      }
      {
        size_t bo = (((size_t)(s & 1) * 16 + g) * 1024 + 2 * tid) * 4;
        u32x4_t qa, qb;
        pollpair_dual(zexch2 + bo, zexch + bo, seq, &qa, &qb);
        scatterPair(buf + 4096, 2 * tid, qa, qb);
      }
      __syncthreads();                                  // BAR_2
      bf16x8_t zfr[8];
#pragma unroll
      for (int kk = 0; kk < 8; ++kk)
        zfr[kk] = *reinterpret_cast<const bf16x8_t*>(buf + 4096 + kk * 512 + l * 8);
      f32x4_t acc = {0.f, 0.f, 0.f, 0.f};
#pragma unroll
      for (int kk = 0; kk < 8; ++kk) acc = mfma16(zfr[kk], wzf[kk], acc);
      const u16* nyp = (const u16*)&nsv;
      u16 yv[4], pv[4];
      int base = fslot(col, m2b);
#pragma unroll
      for (int r = 0; r < 4; ++r) {
        int m2 = m2b + r;
        float u = acc[r] + bzr + r1v[r];
        float msb = sc[16 + m2] * sigm(r0v[r]);
        float yn = (1.0f - msb) * yc[r] + msb * tanh_f(u);
        float ypn = fmaf(bf2f(nyp[r]), sc[m2], yn);
        yc[r] = ypn; ylast[r] = yn;
        yv[r] = f2bf(yn); pv[r] = f2bf(ypn);
        buf[base + 8 * r] = yv[r];
      }
      uint32_t wy0 = (uint32_t)yv[0] | ((uint32_t)yv[1] << 16);
      uint32_t wy1 = (uint32_t)yv[2] | ((uint32_t)yv[3] << 16);
      size_t so = (((size_t)((s + 1) & 1) * 16 + g) * 1024 + half * 512 + tid) * 4;
      publish(yexch + so, yexch2 + so, wy0, wy1, gb + (uint32_t)s + 2u);
      if (d == 9) {
        uint2 pp = {(uint32_t)pv[0] | ((uint32_t)pv[1] << 16),
                    (uint32_t)pv[2] | ((uint32_t)pv[3] << 16)};
        *reinterpret_cast<uint2*>(Ypack + (size_t)(tl * 16 + g) * 4096 + (half * 512 + tid) * 4) = pp;
      }
    }
#pragma unroll
    for (int r = 0; r < 4; ++r) {
      int m2 = m2b + r;
      ystate[(size_t)(g * 16 + m2) * 256 + col] = yc[r];
      ypstate[(size_t)(g * 16 + m2) * 256 + col] = ylast[r];
    }
  }
}

// out[t] = Y[t] @ W_c^T + b_c.  Ypack is C/D-order; transpose via LDS.
__global__ __launch_bounds__(512) void k_out(const u16* __restrict__ Ypack, const u16* __restrict__ Wcpack,
                                             const float* __restrict__ b_c, float* __restrict__ out, int t0) {
  __shared__ u16 yl[4 * 4096];
  int tl = blockIdx.x; int mh = blockIdx.y;
  int tid = threadIdx.x; int l = tid & 63; int wv = tid >> 6;
  for (int i = tid; i < 4096; i += 512) {
    int pg = i >> 10; int j = i & 1023;
    uint2 v = *reinterpret_cast<const uint2*>(
        Ypack + ((size_t)(tl * 16 + mh * 4 + pg)) * 4096 + (size_t)j * 4);
    int wvp = (j >> 6) & 7, lp = j & 63, hf = j >> 9;
    int colp = hf * 128 + wvp * 16 + (lp & 15);
    int mb = 4 * (lp >> 4);
    int base = pg * 4096 + fslot(colp, mb);
    yl[base] = (u16)(v.x & 0xffffu);
    yl[base + 8] = (u16)(v.x >> 16);
    yl[base + 16] = (u16)(v.y & 0xffffu);
    yl[base + 24] = (u16)(v.y >> 16);
  }
  __syncthreads();
  int gl = wv >> 1; int nh = wv & 1;
  int mt = mh * 4 + gl;
  bf16x8_t af[8];
#pragma unroll
  for (int kk = 0; kk < 8; ++kk)
    af[kk] = *reinterpret_cast<const bf16x8_t*>(yl + gl * 4096 + kk * 512 + l * 8);
#pragma unroll 1
  for (int ntl = 0; ntl < 8; ++ntl) {
    int nt = nh * 8 + ntl;
    f32x4_t acc = {0.f, 0.f, 0.f, 0.f};
    const u16* bp = Wcpack + ((size_t)nt * 8 * 64 + l) * 8;
#pragma unroll
    for (int kk = 0; kk < 8; ++kk) {
      bf16x8_t bfr = *reinterpret_cast<const bf16x8_t*>(bp + kk * 512);
      acc = mfma16(af[kk], bfr, acc);
    }
    int n = (nt << 4) | (l & 15);
    float bc = b_c[n];
#pragma unroll
    for (int r = 0; r < 4; ++r) {
      int m = (mt << 4) + ((l >> 4) << 2) + r;
      out[((size_t)(t0 + tl) * 256 + m) * 256 + n] = acc[r] + bc;
    }
  }
}

// ---------------------------------------------------------------------------
extern "C" void kernel_launch(void* const* d_in, const int* in_sizes, int n_in,
                              void* d_out, int out_size, void* d_ws, size_t ws_size,
                              hipStream_t stream) {
  const float* input = (const float*)d_in[0];
  const float* dt    = (const float*)d_in[1];
  const float* W_i   = (const float*)d_in[2];
  const float* b_i   = (const float*)d_in[3];
  const float* W_h   = (const float*)d_in[4];
  const float* b_h   = (const float*)d_in[5];
  const float* W_z   = (const float*)d_in[6];
  const float* b_z   = (const float*)d_in[7];
  const float* W_dt  = (const float*)d_in[8];
  const float* b_dt  = (const float*)d_in[9];
  const float* W_c   = (const float*)d_in[10];
  const float* b_c   = (const float*)d_in[11];
  const float* W_s   = (const float*)d_in[12];
  const float* b_s   = (const float*)d_in[13];
  float* out = (float*)d_out;

  char* ws = (char*)d_ws;
  size_t off = 0;
  auto alloc = [&](size_t bytes) -> char* {
    char* p = ws + off; off = (off + bytes + 255) & ~(size_t)255; return p;
  };
  u16* Epack   = (u16*)alloc((size_t)112 * 4096 * 2);
  u16* Wipack  = (u16*)alloc((size_t)64 * 4096 * 2);
  u16* Wzpack  = (u16*)alloc((size_t)16 * 4096 * 2);
  u16* Wcpack  = (u16*)alloc((size_t)16 * 4096 * 2);
  u16* Wspack  = (u16*)alloc((size_t)32 * 16 * 512 * 2);
  u16* E2pack  = (u16*)alloc((size_t)64 * 4096 * 2);
  float* bip   = (float*)alloc(1024 * 4);
  float* biasD0= (float*)alloc(1024 * 4);
  float* biasDn= (float*)alloc(1024 * 4);
  float* Wic   = (float*)alloc((size_t)1024 * 256 * 4);
  float* ystate= (float*)alloc((size_t)256 * 256 * 4);
  float* ypstate=(float*)alloc((size_t)256 * 256 * 4);
  float* zstate= (float*)alloc((size_t)256 * 256 * 4);
  uint32_t* yexch  = (uint32_t*)alloc((size_t)2 * 16 * 1024 * 16);
  uint32_t* yexch2 = (uint32_t*)alloc((size_t)2 * 16 * 1024 * 16);
  uint32_t* zexch  = (uint32_t*)alloc((size_t)2 * 16 * 1024 * 16);
  uint32_t* zexch2 = (uint32_t*)alloc((size_t)2 * 16 * 1024 * 16);
  size_t fixed = off;
  // per-Tc memory: singles (Apack 256KB + nyA 128KB per slot, Ypack) +
  // doubled (Sny,Snz per slot; HN per step; XI, inpPack per tl)
  size_t per_t = (size_t)10 * (262144 + 131072)            // Apack + nyA
               + (size_t)2 * 10 * (131072 + 131072)        // Sny + Snz (x2)
               + (size_t)2 * 10 * 393216                   // HN (x2)
               + (size_t)2 * (524288 + 131072)             // XI + inpPack (x2)
               + 131072;                                    // Ypack
  size_t per_fix = 262144 + 131072;                        // +1 slot (Apack,nyA,Sn x2)
  int Tc = 1;
  if (ws_size > fixed + per_t + per_fix + (size_t)2 * 262144) {
    size_t n = (ws_size - fixed - per_fix - (size_t)2 * 262144) / per_t;
    Tc = (n > 128) ? 128 : (int)n;
  }
  if (Tc < 1) Tc = 1;
  int maxslots = Tc * 10 + 1;
  size_t snyS = (size_t)maxslots * 65536;          // u16 per parity set
  size_t hnS  = (size_t)Tc * 10 * 196608;
  size_t xiS  = (size_t)Tc * 262144;
  size_t inpS = (size_t)Tc * 65536;
  u16* Apack   = (u16*)alloc((size_t)maxslots * 131072 * 2);
  u16* nyA     = (u16*)alloc((size_t)maxslots * 65536 * 2);
  u16* Sny     = (u16*)alloc(snyS * 2 * 2);
  u16* Snz     = (u16*)alloc(snyS * 2 * 2);
  u16* HNpack  = (u16*)alloc(hnS * 2 * 2);
  u16* XIpack  = (u16*)alloc(xiS * 2 * 2);
  u16* inpPack = (u16*)alloc(inpS * 2 * 2);
  u16* Ypack   = (u16*)alloc((size_t)Tc * 65536 * 2);

  (void)hipFuncSetAttribute((const void*)k_mega, hipFuncAttributeMaxDynamicSharedMemorySize,
                            R_LDS_BYTES);

  k_prep<<<1024, 256, 0, stream>>>(W_i, W_c, b_i, b_c, Wic, bip);
  k_bias<<<4, 256, 0, stream>>>(b_i, bip, b_h, biasD0, biasDn);
  k_packw<<<(112 * 8 * 64) / 256, 256, 0, stream>>>(Wic, 1024, W_h, Epack, 1792, 256);
  k_packw<<<(64 * 8 * 64) / 256, 256, 0, stream>>>(W_i, 1024, (const float*)nullptr, Wipack, 1024, 256);
  k_packw<<<(16 * 8 * 64) / 256, 256, 0, stream>>>(W_z, 256, (const float*)nullptr, Wzpack, 256, 256);
  k_packw<<<(16 * 8 * 64) / 256, 256, 0, stream>>>(W_c, 256, (const float*)nullptr, Wcpack, 256, 256);
  k_packw<<<(32 * 16 * 64) / 256, 256, 0, stream>>>(W_s, 512, (const float*)nullptr, Wspack, 512, 512);
  k_packe2<<<128, 256, 0, stream>>>(Wic, W_h, E2pack);

  // ---- prologue: chunk 0 noise pipeline into parity 0 ----
  int Tcc0 = (128 < Tc) ? 128 : Tc;
  int slots0 = Tcc0 * 10 + 1;
  k_gen<<<slots0 * 128, 1024, 0, stream>>>(Apack, -1);
  dim3 g2(slots0, 4);
  k_sgemm<<<g2, 512, 0, stream>>>(Apack, Wspack, b_s, Sny, Snz, nyA);
  dim3 g3(Tcc0 * 10, 6);
  k_hn<<<g3, 512, 0, stream>>>(nyA, Epack, HNpack, 0);
  int totalA = Tcc0 * 16 * 8 * 64;
  k_packa<<<(totalA + 255) / 256, 256, 0, stream>>>(input, 0, Tcc0, inpPack);
  dim3 gx(Tcc0, 8);
  k_xi<<<gx, 512, 0, stream>>>(inpPack, Wipack, XIpack);

  int c = 0;
  for (int t0 = 0; t0 < 128; t0 += Tc, ++c) {
    int Tcc = (128 - t0 < Tc) ? (128 - t0) : Tc;
    int pc = c & 1;
    int t0b = t0 + Tcc;
    int Tcc2 = (128 - t0b < Tc) ? (128 - t0b) : Tc;   // <=0 on last chunk
    int pn = (c + 1) & 1;
    k_mega<<<256, 512, R_LDS_BYTES, stream>>>(
        dt, Epack, Wzpack, E2pack, HNpack, XIpack,
        biasD0, biasDn, b_z, W_dt, b_dt, Sny, Snz,
        Ypack, ystate, ypstate, zstate,
        yexch, yexch2, zexch, zexch2,
        input, Wipack, Wspack, b_s, Apack, nyA, inpPack,
        t0, Tcc, pc, t0b, Tcc2, pn,
        (unsigned long)snyS, (unsigned long)hnS, (unsigned long)xiS, (unsigned long)inpS);
    dim3 ge(Tcc, 4);
    k_out<<<ge, 512, 0, stream>>>(Ypack, Wcpack, b_c, out, t0);
  }
}